// Round 2
// baseline (855.310 us; speedup 1.0000x reference)
//
#include <hip/hip_runtime.h>
#include <math.h>

#define DIN 17
#define DH  128
#define NH  4
#define CC  32
#define NL  3
#define NEG 0.2f

// ---------------- tiny per-layer edge-projection scalars ----------------
// p[l,h] = sum_{d,c} enc_edge_w[d] * We[l,d,h*32+c] * a_edge[l,h,c]
// q[l,h] = same with enc_edge_b
__global__ void pq_kernel(const float* __restrict__ ew, const float* __restrict__ eb,
                          const float* __restrict__ We, const float* __restrict__ ae,
                          float* __restrict__ pq) {
    int lh = blockIdx.x;            // 0..11
    int l = lh >> 2, h = lh & 3;
    int t = threadIdx.x;            // 64
    const float* Wel = We + l * DH * DH;
    const float* ael = ae + l * DH + h * CC;
    float p = 0.f, q = 0.f;
    for (int d = t; d < DH; d += 64) {
        const float* row = Wel + d * DH + h * CC;
        float wp = 0.f;
        for (int c = 0; c < CC; ++c) wp += row[c] * ael[c];
        p += ew[d] * wp;
        q += eb[d] * wp;
    }
    for (int o = 32; o > 0; o >>= 1) { p += __shfl_down(p, o, 64); q += __shfl_down(q, o, 64); }
    if (t == 0) { pq[lh * 2 + 0] = p; pq[lh * 2 + 1] = q; }
}

// ---------------- node encoder: h = x @ Wn + bn (32 rows/block) ----------------
__global__ void enc_kernel(const float* __restrict__ x, const float* __restrict__ W,
                           const float* __restrict__ b, float* __restrict__ h, int N) {
    __shared__ float wl[DIN][DH];
    __shared__ float xs[32][DIN];
    int tid = threadIdx.x;          // 256
    int row0 = blockIdx.x * 32;
    for (int i = tid; i < DIN * DH; i += 256) wl[i / DH][i % DH] = W[i];
    for (int i = tid; i < 32 * DIN; i += 256) {
        int r = i / DIN, k = i % DIN;
        int rr = row0 + r; if (rr > N - 1) rr = N - 1;
        xs[r][k] = x[(size_t)rr * DIN + k];
    }
    __syncthreads();
    int c = tid & 127;
    int g = tid >> 7;
    float bias = b[c];
    #pragma unroll
    for (int r = 0; r < 16; ++r) {
        int row = row0 + g * 16 + r;
        if (row >= N) break;
        float acc = bias;
        #pragma unroll
        for (int k = 0; k < DIN; ++k) acc += xs[g * 16 + r][k] * wl[k][c];
        h[(size_t)row * DH + c] = acc;
    }
}

// ---------------- per-layer node transform: h1 = h@W + fused att reductions ----------
// 256 threads: c = tid&127 (output channel), g = tid>>7 (row half). 32 rows/block.
// W column chunk kept in VGPRs; row data read as wave-uniform float4 loads.
__global__ void __launch_bounds__(256) layer_node(
        const float* __restrict__ h, const float* __restrict__ W,
        const float* __restrict__ asv, const float* __restrict__ adv,
        float* __restrict__ h1, float* __restrict__ as_, float* __restrict__ ad_,
        int N) {
    int tid = threadIdx.x;
    int c = tid & 127;
    int g = __builtin_amdgcn_readfirstlane(tid >> 7);
    int row0 = blockIdx.x * 32 + g * 16;

    float acc[16];
    #pragma unroll
    for (int r = 0; r < 16; ++r) acc[r] = 0.f;

    #pragma unroll
    for (int kh = 0; kh < 2; ++kh) {
        float wreg[64];
        #pragma unroll
        for (int k = 0; k < 64; ++k) wreg[k] = W[(kh * 64 + k) * DH + c];
        #pragma unroll
        for (int r = 0; r < 16; ++r) {
            int row = row0 + r; if (row > N - 1) row = N - 1;
            const float4* rp = (const float4*)(h + (size_t)row * DH + kh * 64);
            float ra = acc[r];
            #pragma unroll
            for (int k4 = 0; k4 < 16; ++k4) {
                float4 v = rp[k4];
                ra = fmaf(v.x, wreg[k4 * 4 + 0], ra);
                ra = fmaf(v.y, wreg[k4 * 4 + 1], ra);
                ra = fmaf(v.z, wreg[k4 * 4 + 2], ra);
                ra = fmaf(v.w, wreg[k4 * 4 + 3], ra);
            }
            acc[r] = ra;
        }
    }

    float a_s = asv[c], a_d = adv[c];
    #pragma unroll
    for (int r = 0; r < 16; ++r) {
        int row = row0 + r;
        bool valid = row < N;
        if (valid) h1[(size_t)row * DH + c] = acc[r];
        float ps = acc[r] * a_s, pd = acc[r] * a_d;
        #pragma unroll
        for (int o = 16; o > 0; o >>= 1) {
            ps += __shfl_down(ps, o, 32);
            pd += __shfl_down(pd, o, 32);
        }
        if (valid && (c & 31) == 0) {
            as_[row * NH + (c >> 5)] = ps;
            ad_[row * NH + (c >> 5)] = pd;
        }
    }
}

// ---------------- degree + edge-attr sum per dst ----------------
__global__ void deg_kernel(const int* __restrict__ ei, const float* __restrict__ ea,
                           int* __restrict__ deg, float* __restrict__ asum, int E) {
    int e = blockIdx.x * 256 + threadIdx.x;
    if (e >= E) return;
    int d = ei[E + e];
    atomicAdd(&deg[d], 1);
    atomicAdd(&asum[d], ea[e]);
}

// ---------------- 3-kernel exclusive scan over deg ----------------
__global__ void scan1(const int* __restrict__ deg, int* __restrict__ offs,
                      int* __restrict__ bsum, int N) {
    __shared__ int buf[1024];
    int b = blockIdx.x, t = threadIdx.x, i = b * 1024 + t;
    int v = (i < N) ? deg[i] : 0;
    buf[t] = v;
    __syncthreads();
    int val = v;
    for (int o = 1; o < 1024; o <<= 1) {
        int add = (t >= o) ? buf[t - o] : 0;
        __syncthreads();
        val += add;
        buf[t] = val;
        __syncthreads();
    }
    if (i < N) offs[i] = val - v;
    if (t == 1023) bsum[b] = val;
}

__global__ void scan2(const int* __restrict__ bsum, int* __restrict__ boff, int nb) {
    if (threadIdx.x == 0) {
        int s = 0;
        for (int b = 0; b < nb; ++b) { boff[b] = s; s += bsum[b]; }
    }
}

__global__ void scan3(int* __restrict__ offs, int* __restrict__ cursor,
                      const int* __restrict__ boff, int N) {
    int i = blockIdx.x * 1024 + threadIdx.x;
    if (i >= N) return;
    int v = offs[i] + boff[blockIdx.x];
    offs[i] = v;
    cursor[i] = v;
}

// ---------------- scatter edges into CSR by dst (packed int2{src, attr}) ----------
__global__ void scatter_kernel(const int* __restrict__ ei, const float* __restrict__ ea,
                               int* __restrict__ cursor, int2* __restrict__ csr, int E) {
    int e = blockIdx.x * 256 + threadIdx.x;
    if (e >= E) return;
    int d = ei[E + e];
    int pos = atomicAdd(&cursor[d], 1);
    int2 p; p.x = ei[e]; p.y = __float_as_int(ea[e]);
    csr[pos] = p;
}

// ---------------- per-node attention + aggregation: online softmax, 1 wave/node ----
__global__ void agg_kernel(const float* __restrict__ h1, const float* __restrict__ as_,
                           const float* __restrict__ ad_, const int* __restrict__ offs,
                           const int* __restrict__ deg, const float* __restrict__ asum,
                           const int2* __restrict__ csr,
                           const float* __restrict__ pql, const float* __restrict__ bias,
                           float* __restrict__ hout, int N) {
    int n = blockIdx.x * 4 + (threadIdx.x >> 6);
    if (n >= N) return;
    int lane = threadIdx.x & 63;
    int hd = lane >> 4;
    int c0 = lane * 2;
    int off = offs[n], dg = deg[n];
    float adn = ad_[n * NH + hd];
    float pa = pql[hd * 2 + 0], qa = pql[hd * 2 + 1];

    // self-loop logit (loop attr = mean of incoming edge attrs; exactly 0 if deg==0)
    float sa = asum[n] / fmaxf((float)dg, 1.f);
    float ael = (dg > 0) ? (sa * pa + qa) : 0.f;
    float l0 = as_[n * NH + hd] + adn + ael;
    l0 = (l0 > 0.f) ? l0 : NEG * l0;

    float mx = l0, den = 1.f;
    float2 hv = *(const float2*)(h1 + (size_t)n * DH + c0);
    float a0 = hv.x, a1 = hv.y;

    for (int i = 0; i < dg; ++i) {
        int2 ep = csr[off + i];
        int s = ep.x;
        float a = __int_as_float(ep.y);
        float lg = as_[s * NH + hd] + adn + a * pa + qa;
        lg = (lg > 0.f) ? lg : NEG * lg;
        float nm = fmaxf(mx, lg);
        float sc  = __expf(mx - nm);
        float num = __expf(lg - nm);
        float2 hs = *(const float2*)(h1 + (size_t)s * DH + c0);
        den = den * sc + num;
        a0  = a0  * sc + num * hs.x;
        a1  = a1  * sc + num * hs.y;
        mx = nm;
    }
    float inv = 1.f / (den + 1e-16f);
    float o0 = a0 * inv + bias[c0];
    float o1 = a1 * inv + bias[c0 + 1];
    o0 = (o0 > 0.f) ? o0 : expm1f(o0);   // elu
    o1 = (o1 > 0.f) ? o1 : expm1f(o1);
    hout[(size_t)n * DH + c0] = o0;
    hout[(size_t)n * DH + c0 + 1] = o1;
}

// ---------------- decoder: relu(h@w1+b1)@w2+b2, fully fused ----------------
__global__ void __launch_bounds__(256) dec_kernel(
        const float* __restrict__ h, const float* __restrict__ w1,
        const float* __restrict__ b1, const float* __restrict__ w2,
        const float* __restrict__ b2, float* __restrict__ out, int N) {
    int tid = threadIdx.x;
    int c = tid & 127;
    int g = __builtin_amdgcn_readfirstlane(tid >> 7);
    int row0 = blockIdx.x * 32 + g * 16;

    float acc[16];
    #pragma unroll
    for (int r = 0; r < 16; ++r) acc[r] = 0.f;

    #pragma unroll
    for (int kh = 0; kh < 2; ++kh) {
        float wreg[64];
        #pragma unroll
        for (int k = 0; k < 64; ++k) wreg[k] = w1[(kh * 64 + k) * DH + c];
        #pragma unroll
        for (int r = 0; r < 16; ++r) {
            int row = row0 + r; if (row > N - 1) row = N - 1;
            const float4* rp = (const float4*)(h + (size_t)row * DH + kh * 64);
            float ra = acc[r];
            #pragma unroll
            for (int k4 = 0; k4 < 16; ++k4) {
                float4 v = rp[k4];
                ra = fmaf(v.x, wreg[k4 * 4 + 0], ra);
                ra = fmaf(v.y, wreg[k4 * 4 + 1], ra);
                ra = fmaf(v.z, wreg[k4 * 4 + 2], ra);
                ra = fmaf(v.w, wreg[k4 * 4 + 3], ra);
            }
            acc[r] = ra;
        }
    }

    float bb = b1[c], w20 = w2[c * 2 + 0], w21 = w2[c * 2 + 1];
    __shared__ float part[2][2][16][2];   // [g][wavehalf][r][out]
    int wh = c >> 6;
    #pragma unroll
    for (int r = 0; r < 16; ++r) {
        float hid = fmaxf(acc[r] + bb, 0.f);
        float p0 = hid * w20, p1 = hid * w21;
        #pragma unroll
        for (int o = 32; o > 0; o >>= 1) {
            p0 += __shfl_down(p0, o, 64);
            p1 += __shfl_down(p1, o, 64);
        }
        if ((tid & 63) == 0) { part[g][wh][r][0] = p0; part[g][wh][r][1] = p1; }
    }
    __syncthreads();
    if (tid < 64) {
        int r = tid >> 1, o = tid & 1;      // r in 0..31
        int row = blockIdx.x * 32 + r;
        if (row < N)
            out[row * 2 + o] = part[r >> 4][0][r & 15][o] + part[r >> 4][1][r & 15][o] + b2[o];
    }
}

extern "C" void kernel_launch(void* const* d_in, const int* in_sizes, int n_in,
                              void* d_out, int out_size, void* d_ws, size_t ws_size,
                              hipStream_t stream) {
    const float* x          = (const float*)d_in[0];
    const int*   ei         = (const int*)d_in[1];
    const float* eattr      = (const float*)d_in[2];
    const float* enc_node_w = (const float*)d_in[3];
    const float* enc_node_b = (const float*)d_in[4];
    const float* enc_edge_w = (const float*)d_in[5];
    const float* enc_edge_b = (const float*)d_in[6];
    const float* lin_w      = (const float*)d_in[7];
    const float* lin_edge_w = (const float*)d_in[8];
    const float* att_src    = (const float*)d_in[9];
    const float* att_dst    = (const float*)d_in[10];
    const float* att_edge   = (const float*)d_in[11];
    const float* gat_bias   = (const float*)d_in[12];
    const float* dec_w1     = (const float*)d_in[13];
    const float* dec_b1     = (const float*)d_in[14];
    const float* dec_w2     = (const float*)d_in[15];
    const float* dec_b2     = (const float*)d_in[16];

    const int E = in_sizes[2];          // DE == 1
    const int N = in_sizes[0] / DIN;

    char* w = (char*)d_ws;
    auto alloc = [&](size_t bytes) -> void* {
        void* p = (void*)w;
        w += (bytes + 511) & ~((size_t)511);
        return p;
    };
    float* h      = (float*)alloc((size_t)N * DH * 4);
    float* h1     = (float*)alloc((size_t)N * DH * 4);
    float* as_    = (float*)alloc((size_t)N * NH * 4);
    float* ad_    = (float*)alloc((size_t)N * NH * 4);
    int*   deg    = (int*)alloc((size_t)N * 4);
    float* asum   = (float*)alloc((size_t)N * 4);
    int*   offs   = (int*)alloc((size_t)N * 4);
    int*   cursor = (int*)alloc((size_t)N * 4);
    int*   bsum   = (int*)alloc(64 * 4);
    int*   boff   = (int*)alloc(64 * 4);
    int2*  csr    = (int2*)alloc((size_t)E * 8);
    float* pq     = (float*)alloc(NL * NH * 2 * 4);

    hipMemsetAsync(deg, 0, (size_t)N * 4, stream);
    hipMemsetAsync(asum, 0, (size_t)N * 4, stream);

    pq_kernel<<<NL * NH, 64, 0, stream>>>(enc_edge_w, enc_edge_b, lin_edge_w, att_edge, pq);
    enc_kernel<<<(N + 31) / 32, 256, 0, stream>>>(x, enc_node_w, enc_node_b, h, N);
    deg_kernel<<<(E + 255) / 256, 256, 0, stream>>>(ei, eattr, deg, asum, E);

    int nb = (N + 1023) / 1024;
    scan1<<<nb, 1024, 0, stream>>>(deg, offs, bsum, N);
    scan2<<<1, 64, 0, stream>>>(bsum, boff, nb);
    scan3<<<nb, 1024, 0, stream>>>(offs, cursor, boff, N);
    scatter_kernel<<<(E + 255) / 256, 256, 0, stream>>>(ei, eattr, cursor, csr, E);

    for (int l = 0; l < NL; ++l) {
        layer_node<<<(N + 31) / 32, 256, 0, stream>>>(h, lin_w + (size_t)l * DH * DH,
                                                      att_src + l * DH, att_dst + l * DH,
                                                      h1, as_, ad_, N);
        agg_kernel<<<(N + 3) / 4, 256, 0, stream>>>(h1, as_, ad_, offs, deg, asum, csr,
                                                    pq + l * NH * 2, gat_bias + l * DH, h, N);
    }
    dec_kernel<<<(N + 31) / 32, 256, 0, stream>>>(h, dec_w1, dec_b1, dec_w2, dec_b2,
                                                  (float*)d_out, N);
}

// Round 3
// 648.573 us; speedup vs baseline: 1.3188x; 1.3188x over previous
//
#include <hip/hip_runtime.h>
#include <math.h>

#define DIN 17
#define DH  128
#define NH  4
#define CC  32
#define NL  3
#define NEG 0.2f

// ---------------- tiny per-layer edge-projection scalars ----------------
__global__ void pq_kernel(const float* __restrict__ ew, const float* __restrict__ eb,
                          const float* __restrict__ We, const float* __restrict__ ae,
                          float* __restrict__ pq) {
    int lh = blockIdx.x;            // 0..11
    int l = lh >> 2, h = lh & 3;
    int t = threadIdx.x;            // 64
    const float* Wel = We + l * DH * DH;
    const float* ael = ae + l * DH + h * CC;
    float p = 0.f, q = 0.f;
    for (int d = t; d < DH; d += 64) {
        const float* row = Wel + d * DH + h * CC;
        float wp = 0.f;
        for (int c = 0; c < CC; ++c) wp += row[c] * ael[c];
        p += ew[d] * wp;
        q += eb[d] * wp;
    }
    for (int o = 32; o > 0; o >>= 1) { p += __shfl_down(p, o, 64); q += __shfl_down(q, o, 64); }
    if (t == 0) { pq[lh * 2 + 0] = p; pq[lh * 2 + 1] = q; }
}

// ---------------- node encoder: h = x @ Wn + bn (32 rows/block) ----------------
__global__ void enc_kernel(const float* __restrict__ x, const float* __restrict__ W,
                           const float* __restrict__ b, float* __restrict__ h, int N) {
    __shared__ float wl[DIN][DH];
    __shared__ float xs[32][DIN];
    int tid = threadIdx.x;          // 256
    int row0 = blockIdx.x * 32;
    for (int i = tid; i < DIN * DH; i += 256) wl[i / DH][i % DH] = W[i];
    for (int i = tid; i < 32 * DIN; i += 256) {
        int r = i / DIN, k = i % DIN;
        int rr = row0 + r; if (rr > N - 1) rr = N - 1;
        xs[r][k] = x[(size_t)rr * DIN + k];
    }
    __syncthreads();
    int c = tid & 127;
    int g = tid >> 7;
    float bias = b[c];
    #pragma unroll
    for (int r = 0; r < 16; ++r) {
        int row = row0 + g * 16 + r;
        if (row >= N) break;
        float acc = bias;
        #pragma unroll
        for (int k = 0; k < DIN; ++k) acc += xs[g * 16 + r][k] * wl[k][c];
        h[(size_t)row * DH + c] = acc;
    }
}

// ---------------- per-layer node transform: h1 = h@W + fused att reductions ----------
// 256 threads / 32 rows per block. Rows staged in LDS (coalesced), W chunks in VGPRs,
// compute reads are wave-uniform LDS broadcasts (conflict-free).
__global__ void __launch_bounds__(256) layer_node(
        const float* __restrict__ h, const float* __restrict__ W,
        const float* __restrict__ asv, const float* __restrict__ adv,
        float* __restrict__ h1, float* __restrict__ as_, float* __restrict__ ad_,
        int N) {
    __shared__ __align__(16) float rows[32][DH];
    int tid = threadIdx.x;
    int row0 = blockIdx.x * 32;

    // stage 32 rows, fully coalesced (clamped duplicate of last row for tail block)
    #pragma unroll
    for (int i = 0; i < 4; ++i) {
        int idx = tid + i * 256;        // float4 index 0..1023
        int r = idx >> 5;               // 32 float4 per row
        int cq = idx & 31;
        int gr = row0 + r; if (gr > N - 1) gr = N - 1;
        ((float4*)rows[r])[cq] = ((const float4*)(h + (size_t)gr * DH))[cq];
    }
    __syncthreads();

    int c = tid & 127;
    int g = tid >> 7;                   // wave-uniform (0/1)
    float acc[16];
    #pragma unroll
    for (int r = 0; r < 16; ++r) acc[r] = 0.f;

    for (int kc = 0; kc < 4; ++kc) {    // 32-wide K chunks; wreg indices static
        float wreg[32];
        #pragma unroll
        for (int k = 0; k < 32; ++k) wreg[k] = W[(kc * 32 + k) * DH + c];
        #pragma unroll
        for (int k4 = 0; k4 < 8; ++k4) {
            #pragma unroll
            for (int r = 0; r < 16; ++r) {
                float4 av = ((const float4*)rows[g * 16 + r])[kc * 8 + k4];
                acc[r] = fmaf(av.x, wreg[k4 * 4 + 0], acc[r]);
                acc[r] = fmaf(av.y, wreg[k4 * 4 + 1], acc[r]);
                acc[r] = fmaf(av.z, wreg[k4 * 4 + 2], acc[r]);
                acc[r] = fmaf(av.w, wreg[k4 * 4 + 3], acc[r]);
            }
        }
    }

    float a_s = asv[c], a_d = adv[c];
    #pragma unroll
    for (int r = 0; r < 16; ++r) {
        int row = row0 + g * 16 + r;
        bool valid = row < N;
        if (valid) h1[(size_t)row * DH + c] = acc[r];
        float ps = acc[r] * a_s, pd = acc[r] * a_d;
        #pragma unroll
        for (int o = 16; o > 0; o >>= 1) {
            ps += __shfl_down(ps, o, 32);
            pd += __shfl_down(pd, o, 32);
        }
        if (valid && (c & 31) == 0) {
            as_[row * NH + (c >> 5)] = ps;
            ad_[row * NH + (c >> 5)] = pd;
        }
    }
}

// ---------------- degree + edge-attr sum per dst ----------------
__global__ void deg_kernel(const int* __restrict__ ei, const float* __restrict__ ea,
                           int* __restrict__ deg, float* __restrict__ asum, int E) {
    int e = blockIdx.x * 256 + threadIdx.x;
    if (e >= E) return;
    int d = ei[E + e];
    atomicAdd(&deg[d], 1);
    atomicAdd(&asum[d], ea[e]);
}

// ---------------- 3-kernel exclusive scan over deg ----------------
__global__ void scan1(const int* __restrict__ deg, int* __restrict__ offs,
                      int* __restrict__ bsum, int N) {
    __shared__ int buf[1024];
    int b = blockIdx.x, t = threadIdx.x, i = b * 1024 + t;
    int v = (i < N) ? deg[i] : 0;
    buf[t] = v;
    __syncthreads();
    int val = v;
    for (int o = 1; o < 1024; o <<= 1) {
        int add = (t >= o) ? buf[t - o] : 0;
        __syncthreads();
        val += add;
        buf[t] = val;
        __syncthreads();
    }
    if (i < N) offs[i] = val - v;
    if (t == 1023) bsum[b] = val;
}

__global__ void scan2(const int* __restrict__ bsum, int* __restrict__ boff, int nb) {
    if (threadIdx.x == 0) {
        int s = 0;
        for (int b = 0; b < nb; ++b) { boff[b] = s; s += bsum[b]; }
    }
}

__global__ void scan3(int* __restrict__ offs, int* __restrict__ cursor,
                      const int* __restrict__ boff, int N) {
    int i = blockIdx.x * 1024 + threadIdx.x;
    if (i >= N) return;
    int v = offs[i] + boff[blockIdx.x];
    offs[i] = v;
    cursor[i] = v;
}

// ---------------- scatter edges into CSR by dst (packed int2{src, attr}) ----------
__global__ void scatter_kernel(const int* __restrict__ ei, const float* __restrict__ ea,
                               int* __restrict__ cursor, int2* __restrict__ csr, int E) {
    int e = blockIdx.x * 256 + threadIdx.x;
    if (e >= E) return;
    int d = ei[E + e];
    int pos = atomicAdd(&cursor[d], 1);
    int2 p; p.x = ei[e]; p.y = __float_as_int(ea[e]);
    csr[pos] = p;
}

// ---------------- per-node attention + aggregation: online softmax, unroll-4 ------
__global__ void __launch_bounds__(256) agg_kernel(
        const float* __restrict__ h1, const float* __restrict__ as_,
        const float* __restrict__ ad_, const int* __restrict__ offs,
        const int* __restrict__ deg, const float* __restrict__ asum,
        const int2* __restrict__ csr,
        const float* __restrict__ pql, const float* __restrict__ bias,
        float* __restrict__ hout, int N) {
    int n = blockIdx.x * 4 + (threadIdx.x >> 6);
    if (n >= N) return;
    int lane = threadIdx.x & 63;
    int hd = lane >> 4;
    int c0 = lane * 2;
    int off = offs[n], dg = deg[n];
    float adn = ad_[n * NH + hd];
    float pa = pql[hd * 2 + 0], qa = pql[hd * 2 + 1];

    // self-loop logit (loop attr = mean of incoming edge attrs; exactly 0 if deg==0)
    float sa = asum[n] / fmaxf((float)dg, 1.f);
    float ael = (dg > 0) ? (sa * pa + qa) : 0.f;
    float l0 = as_[n * NH + hd] + adn + ael;
    l0 = fmaxf(l0, NEG * l0);

    float mx = l0, den = 1.f;
    float2 hv = *(const float2*)(h1 + (size_t)n * DH + c0);
    float a0 = hv.x, a1 = hv.y;

    int i = 0;
    for (; i + 4 <= dg; i += 4) {
        int2 e0 = csr[off + i + 0];
        int2 e1 = csr[off + i + 1];
        int2 e2 = csr[off + i + 2];
        int2 e3 = csr[off + i + 3];
        // issue all gathers up front (4-deep MLP)
        float2 g0 = *(const float2*)(h1 + (size_t)e0.x * DH + c0);
        float2 g1 = *(const float2*)(h1 + (size_t)e1.x * DH + c0);
        float2 g2 = *(const float2*)(h1 + (size_t)e2.x * DH + c0);
        float2 g3 = *(const float2*)(h1 + (size_t)e3.x * DH + c0);
        float s0 = as_[e0.x * NH + hd];
        float s1 = as_[e1.x * NH + hd];
        float s2 = as_[e2.x * NH + hd];
        float s3 = as_[e3.x * NH + hd];
        float t0 = s0 + adn + __int_as_float(e0.y) * pa + qa;
        float t1 = s1 + adn + __int_as_float(e1.y) * pa + qa;
        float t2 = s2 + adn + __int_as_float(e2.y) * pa + qa;
        float t3 = s3 + adn + __int_as_float(e3.y) * pa + qa;
        t0 = fmaxf(t0, NEG * t0);
        t1 = fmaxf(t1, NEG * t1);
        t2 = fmaxf(t2, NEG * t2);
        t3 = fmaxf(t3, NEG * t3);
        float nm = fmaxf(fmaxf(mx, fmaxf(t0, t1)), fmaxf(t2, t3));
        float sc = __expf(mx - nm);
        float n0 = __expf(t0 - nm);
        float n1 = __expf(t1 - nm);
        float n2 = __expf(t2 - nm);
        float n3 = __expf(t3 - nm);
        den = den * sc + ((n0 + n1) + (n2 + n3));
        a0  = a0  * sc + ((n0 * g0.x + n1 * g1.x) + (n2 * g2.x + n3 * g3.x));
        a1  = a1  * sc + ((n0 * g0.y + n1 * g1.y) + (n2 * g2.y + n3 * g3.y));
        mx = nm;
    }
    for (; i < dg; ++i) {
        int2 ep = csr[off + i];
        float2 gs = *(const float2*)(h1 + (size_t)ep.x * DH + c0);
        float lg = as_[ep.x * NH + hd] + adn + __int_as_float(ep.y) * pa + qa;
        lg = fmaxf(lg, NEG * lg);
        float nm = fmaxf(mx, lg);
        float sc  = __expf(mx - nm);
        float num = __expf(lg - nm);
        den = den * sc + num;
        a0  = a0  * sc + num * gs.x;
        a1  = a1  * sc + num * gs.y;
        mx = nm;
    }
    float inv = 1.f / (den + 1e-16f);
    float o0 = a0 * inv + bias[c0];
    float o1 = a1 * inv + bias[c0 + 1];
    o0 = (o0 > 0.f) ? o0 : expm1f(o0);   // elu
    o1 = (o1 > 0.f) ? o1 : expm1f(o1);
    hout[(size_t)n * DH + c0] = o0;
    hout[(size_t)n * DH + c0 + 1] = o1;
}

// ---------------- decoder: relu(h@w1+b1)@w2+b2, fully fused ----------------
__global__ void __launch_bounds__(256) dec_kernel(
        const float* __restrict__ h, const float* __restrict__ w1,
        const float* __restrict__ b1, const float* __restrict__ w2,
        const float* __restrict__ b2, float* __restrict__ out, int N) {
    __shared__ __align__(16) float rows[32][DH];
    int tid = threadIdx.x;
    int row0 = blockIdx.x * 32;

    #pragma unroll
    for (int i = 0; i < 4; ++i) {
        int idx = tid + i * 256;
        int r = idx >> 5;
        int cq = idx & 31;
        int gr = row0 + r; if (gr > N - 1) gr = N - 1;
        ((float4*)rows[r])[cq] = ((const float4*)(h + (size_t)gr * DH))[cq];
    }
    __syncthreads();

    int c = tid & 127;
    int g = tid >> 7;
    float acc[16];
    #pragma unroll
    for (int r = 0; r < 16; ++r) acc[r] = 0.f;

    for (int kc = 0; kc < 4; ++kc) {
        float wreg[32];
        #pragma unroll
        for (int k = 0; k < 32; ++k) wreg[k] = w1[(kc * 32 + k) * DH + c];
        #pragma unroll
        for (int k4 = 0; k4 < 8; ++k4) {
            #pragma unroll
            for (int r = 0; r < 16; ++r) {
                float4 av = ((const float4*)rows[g * 16 + r])[kc * 8 + k4];
                acc[r] = fmaf(av.x, wreg[k4 * 4 + 0], acc[r]);
                acc[r] = fmaf(av.y, wreg[k4 * 4 + 1], acc[r]);
                acc[r] = fmaf(av.z, wreg[k4 * 4 + 2], acc[r]);
                acc[r] = fmaf(av.w, wreg[k4 * 4 + 3], acc[r]);
            }
        }
    }

    float bb = b1[c], w20 = w2[c * 2 + 0], w21 = w2[c * 2 + 1];
    __shared__ float part[2][2][16][2];   // [g][wavehalf][r][out]
    int wh = (c >> 6);
    #pragma unroll
    for (int r = 0; r < 16; ++r) {
        float hid = fmaxf(acc[r] + bb, 0.f);
        float p0 = hid * w20, p1 = hid * w21;
        #pragma unroll
        for (int o = 32; o > 0; o >>= 1) {
            p0 += __shfl_down(p0, o, 64);
            p1 += __shfl_down(p1, o, 64);
        }
        if ((tid & 63) == 0) { part[g][wh][r][0] = p0; part[g][wh][r][1] = p1; }
    }
    __syncthreads();
    if (tid < 64) {
        int r = tid >> 1, o = tid & 1;      // r in 0..31
        int row = blockIdx.x * 32 + r;
        if (row < N)
            out[row * 2 + o] = part[r >> 4][0][r & 15][o] + part[r >> 4][1][r & 15][o] + b2[o];
    }
}

extern "C" void kernel_launch(void* const* d_in, const int* in_sizes, int n_in,
                              void* d_out, int out_size, void* d_ws, size_t ws_size,
                              hipStream_t stream) {
    const float* x          = (const float*)d_in[0];
    const int*   ei         = (const int*)d_in[1];
    const float* eattr      = (const float*)d_in[2];
    const float* enc_node_w = (const float*)d_in[3];
    const float* enc_node_b = (const float*)d_in[4];
    const float* enc_edge_w = (const float*)d_in[5];
    const float* enc_edge_b = (const float*)d_in[6];
    const float* lin_w      = (const float*)d_in[7];
    const float* lin_edge_w = (const float*)d_in[8];
    const float* att_src    = (const float*)d_in[9];
    const float* att_dst    = (const float*)d_in[10];
    const float* att_edge   = (const float*)d_in[11];
    const float* gat_bias   = (const float*)d_in[12];
    const float* dec_w1     = (const float*)d_in[13];
    const float* dec_b1     = (const float*)d_in[14];
    const float* dec_w2     = (const float*)d_in[15];
    const float* dec_b2     = (const float*)d_in[16];

    const int E = in_sizes[2];          // DE == 1
    const int N = in_sizes[0] / DIN;

    char* w = (char*)d_ws;
    auto alloc = [&](size_t bytes) -> void* {
        void* p = (void*)w;
        w += (bytes + 511) & ~((size_t)511);
        return p;
    };
    float* h      = (float*)alloc((size_t)N * DH * 4);
    float* h1     = (float*)alloc((size_t)N * DH * 4);
    float* as_    = (float*)alloc((size_t)N * NH * 4);
    float* ad_    = (float*)alloc((size_t)N * NH * 4);
    int*   deg    = (int*)alloc((size_t)N * 4);
    float* asum   = (float*)alloc((size_t)N * 4);
    int*   offs   = (int*)alloc((size_t)N * 4);
    int*   cursor = (int*)alloc((size_t)N * 4);
    int*   bsum   = (int*)alloc(64 * 4);
    int*   boff   = (int*)alloc(64 * 4);
    int2*  csr    = (int2*)alloc((size_t)E * 8);
    float* pq     = (float*)alloc(NL * NH * 2 * 4);

    hipMemsetAsync(deg, 0, (size_t)N * 4, stream);
    hipMemsetAsync(asum, 0, (size_t)N * 4, stream);

    pq_kernel<<<NL * NH, 64, 0, stream>>>(enc_edge_w, enc_edge_b, lin_edge_w, att_edge, pq);
    enc_kernel<<<(N + 31) / 32, 256, 0, stream>>>(x, enc_node_w, enc_node_b, h, N);
    deg_kernel<<<(E + 255) / 256, 256, 0, stream>>>(ei, eattr, deg, asum, E);

    int nb = (N + 1023) / 1024;
    scan1<<<nb, 1024, 0, stream>>>(deg, offs, bsum, N);
    scan2<<<1, 64, 0, stream>>>(bsum, boff, nb);
    scan3<<<nb, 1024, 0, stream>>>(offs, cursor, boff, N);
    scatter_kernel<<<(E + 255) / 256, 256, 0, stream>>>(ei, eattr, cursor, csr, E);

    for (int l = 0; l < NL; ++l) {
        layer_node<<<(N + 31) / 32, 256, 0, stream>>>(h, lin_w + (size_t)l * DH * DH,
                                                      att_src + l * DH, att_dst + l * DH,
                                                      h1, as_, ad_, N);
        agg_kernel<<<(N + 3) / 4, 256, 0, stream>>>(h1, as_, ad_, offs, deg, asum, csr,
                                                    pq + l * NH * 2, gat_bias + l * DH, h, N);
    }
    dec_kernel<<<(N + 31) / 32, 256, 0, stream>>>(h, dec_w1, dec_b1, dec_w2, dec_b2,
                                                  (float*)d_out, N);
}

// Round 4
// 504.300 us; speedup vs baseline: 1.6960x; 1.2861x over previous
//
#include <hip/hip_runtime.h>
#include <math.h>

#define DIN 17
#define DH  128
#define NH  4
#define CC  32
#define NL  3
#define NEG 0.2f

// ---------------- tiny per-layer edge-projection scalars ----------------
__global__ void pq_kernel(const float* __restrict__ ew, const float* __restrict__ eb,
                          const float* __restrict__ We, const float* __restrict__ ae,
                          float* __restrict__ pq) {
    int lh = blockIdx.x;            // 0..11
    int l = lh >> 2, h = lh & 3;
    int t = threadIdx.x;            // 64
    const float* Wel = We + l * DH * DH;
    const float* ael = ae + l * DH + h * CC;
    float p = 0.f, q = 0.f;
    for (int d = t; d < DH; d += 64) {
        const float* row = Wel + d * DH + h * CC;
        float wp = 0.f;
        for (int c = 0; c < CC; ++c) wp += row[c] * ael[c];
        p += ew[d] * wp;
        q += eb[d] * wp;
    }
    for (int o = 32; o > 0; o >>= 1) { p += __shfl_down(p, o, 64); q += __shfl_down(q, o, 64); }
    if (t == 0) { pq[lh * 2 + 0] = p; pq[lh * 2 + 1] = q; }
}

// ---------------- node encoder: h = x @ Wn + bn (32 rows/block) ----------------
__global__ void enc_kernel(const float* __restrict__ x, const float* __restrict__ W,
                           const float* __restrict__ b, float* __restrict__ h, int N) {
    __shared__ float wl[DIN][DH];
    __shared__ float xs[32][DIN];
    int tid = threadIdx.x;          // 256
    int row0 = blockIdx.x * 32;
    for (int i = tid; i < DIN * DH; i += 256) wl[i / DH][i % DH] = W[i];
    for (int i = tid; i < 32 * DIN; i += 256) {
        int r = i / DIN, k = i % DIN;
        int rr = row0 + r; if (rr > N - 1) rr = N - 1;
        xs[r][k] = x[(size_t)rr * DIN + k];
    }
    __syncthreads();
    int c = tid & 127;
    int g = tid >> 7;
    float bias = b[c];
    #pragma unroll
    for (int r = 0; r < 16; ++r) {
        int row = row0 + g * 16 + r;
        if (row >= N) break;
        float acc = bias;
        #pragma unroll
        for (int k = 0; k < DIN; ++k) acc += xs[g * 16 + r][k] * wl[k][c];
        h[(size_t)row * DH + c] = acc;
    }
}

// ---------------- per-layer node transform: h1 = h@W + fused att reductions ----------
// 256 threads / 32 rows per block. Lane owns 4 cols x 4 rows (acc[4][4]):
// 64 FMA per 4-wide K chunk per lane vs 4 broadcast ds_read_b128 + 4 W float4.
__global__ void __launch_bounds__(256) layer_node(
        const float* __restrict__ h, const float* __restrict__ W,
        const float* __restrict__ asv, const float* __restrict__ adv,
        float* __restrict__ h1, float* __restrict__ as_, float* __restrict__ ad_,
        int N) {
    __shared__ __align__(16) float rows[32][DH];
    int tid = threadIdx.x;
    int row0 = blockIdx.x * 32;

    // stage 32 rows, fully coalesced (clamped duplicate of last row for tail block)
    #pragma unroll
    for (int i = 0; i < 4; ++i) {
        int idx = tid + i * 256;        // float4 index 0..1023
        int r = idx >> 5;               // 32 float4 per row
        int cq = idx & 31;
        int gr = row0 + r; if (gr > N - 1) gr = N - 1;
        ((float4*)rows[r])[cq] = ((const float4*)(h + (size_t)gr * DH))[cq];
    }
    __syncthreads();

    int wv_ = tid >> 6;                 // wave 0..3
    int lane = tid & 63;
    int cg = lane & 31;                 // col group: cols cg*4..cg*4+3
    int rh = lane >> 5;                 // row half within wave
    int rbase = wv_ * 8 + rh * 4;       // 4 rows: rbase..rbase+3

    float acc[4][4];
    #pragma unroll
    for (int r = 0; r < 4; ++r)
        #pragma unroll
        for (int c = 0; c < 4; ++c) acc[r][c] = 0.f;

    #pragma unroll 2
    for (int kc = 0; kc < 32; ++kc) {   // K chunks of 4
        float4 wv0 = ((const float4*)(W + (kc * 4 + 0) * DH))[cg];
        float4 wv1 = ((const float4*)(W + (kc * 4 + 1) * DH))[cg];
        float4 wv2 = ((const float4*)(W + (kc * 4 + 2) * DH))[cg];
        float4 wv3 = ((const float4*)(W + (kc * 4 + 3) * DH))[cg];
        #pragma unroll
        for (int r = 0; r < 4; ++r) {
            float4 rv = ((const float4*)rows[rbase + r])[kc];
            acc[r][0] = fmaf(rv.x, wv0.x, acc[r][0]);
            acc[r][1] = fmaf(rv.x, wv0.y, acc[r][1]);
            acc[r][2] = fmaf(rv.x, wv0.z, acc[r][2]);
            acc[r][3] = fmaf(rv.x, wv0.w, acc[r][3]);
            acc[r][0] = fmaf(rv.y, wv1.x, acc[r][0]);
            acc[r][1] = fmaf(rv.y, wv1.y, acc[r][1]);
            acc[r][2] = fmaf(rv.y, wv1.z, acc[r][2]);
            acc[r][3] = fmaf(rv.y, wv1.w, acc[r][3]);
            acc[r][0] = fmaf(rv.z, wv2.x, acc[r][0]);
            acc[r][1] = fmaf(rv.z, wv2.y, acc[r][1]);
            acc[r][2] = fmaf(rv.z, wv2.z, acc[r][2]);
            acc[r][3] = fmaf(rv.z, wv2.w, acc[r][3]);
            acc[r][0] = fmaf(rv.w, wv3.x, acc[r][0]);
            acc[r][1] = fmaf(rv.w, wv3.y, acc[r][1]);
            acc[r][2] = fmaf(rv.w, wv3.z, acc[r][2]);
            acc[r][3] = fmaf(rv.w, wv3.w, acc[r][3]);
        }
    }

    float4 as4 = ((const float4*)asv)[cg];
    float4 ad4 = ((const float4*)adv)[cg];
    int head = cg >> 3;
    #pragma unroll
    for (int r = 0; r < 4; ++r) {
        int row = row0 + rbase + r;
        bool valid = row < N;
        if (valid) {
            float4 o; o.x = acc[r][0]; o.y = acc[r][1]; o.z = acc[r][2]; o.w = acc[r][3];
            ((float4*)(h1 + (size_t)row * DH))[cg] = o;
        }
        float ps = acc[r][0] * as4.x + acc[r][1] * as4.y + acc[r][2] * as4.z + acc[r][3] * as4.w;
        float pd = acc[r][0] * ad4.x + acc[r][1] * ad4.y + acc[r][2] * ad4.z + acc[r][3] * ad4.w;
        #pragma unroll
        for (int o = 4; o > 0; o >>= 1) {
            ps += __shfl_down(ps, o, 8);
            pd += __shfl_down(pd, o, 8);
        }
        if (valid && (lane & 7) == 0) {
            as_[row * NH + head] = ps;
            ad_[row * NH + head] = pd;
        }
    }
}

// ---------------- degree + edge-attr sum per dst ----------------
__global__ void deg_kernel(const int* __restrict__ ei, const float* __restrict__ ea,
                           int* __restrict__ deg, float* __restrict__ asum, int E) {
    int e = blockIdx.x * 256 + threadIdx.x;
    if (e >= E) return;
    int d = ei[E + e];
    atomicAdd(&deg[d], 1);
    atomicAdd(&asum[d], ea[e]);
}

// ---------------- 3-kernel exclusive scan over deg ----------------
__global__ void scan1(const int* __restrict__ deg, int* __restrict__ offs,
                      int* __restrict__ bsum, int N) {
    __shared__ int buf[1024];
    int b = blockIdx.x, t = threadIdx.x, i = b * 1024 + t;
    int v = (i < N) ? deg[i] : 0;
    buf[t] = v;
    __syncthreads();
    int val = v;
    for (int o = 1; o < 1024; o <<= 1) {
        int add = (t >= o) ? buf[t - o] : 0;
        __syncthreads();
        val += add;
        buf[t] = val;
        __syncthreads();
    }
    if (i < N) offs[i] = val - v;
    if (t == 1023) bsum[b] = val;
}

__global__ void scan2(const int* __restrict__ bsum, int* __restrict__ boff, int nb) {
    if (threadIdx.x == 0) {
        int s = 0;
        for (int b = 0; b < nb; ++b) { boff[b] = s; s += bsum[b]; }
    }
}

__global__ void scan3(int* __restrict__ offs, int* __restrict__ cursor,
                      const int* __restrict__ boff, int N) {
    int i = blockIdx.x * 1024 + threadIdx.x;
    if (i >= N) return;
    int v = offs[i] + boff[blockIdx.x];
    offs[i] = v;
    cursor[i] = v;
}

// ---------------- scatter edges into CSR by dst (packed int2{src, attr}) ----------
__global__ void scatter_kernel(const int* __restrict__ ei, const float* __restrict__ ea,
                               int* __restrict__ cursor, int2* __restrict__ csr, int E) {
    int e = blockIdx.x * 256 + threadIdx.x;
    if (e >= E) return;
    int d = ei[E + e];
    int pos = atomicAdd(&cursor[d], 1);
    int2 p; p.x = ei[e]; p.y = __float_as_int(ea[e]);
    csr[pos] = p;
}

// ---------------- per-node attention + aggregation: online softmax, unroll-4 ------
__global__ void __launch_bounds__(256) agg_kernel(
        const float* __restrict__ h1, const float* __restrict__ as_,
        const float* __restrict__ ad_, const int* __restrict__ offs,
        const int* __restrict__ deg, const float* __restrict__ asum,
        const int2* __restrict__ csr,
        const float* __restrict__ pql, const float* __restrict__ bias,
        float* __restrict__ hout, int N) {
    int n = blockIdx.x * 4 + (threadIdx.x >> 6);
    if (n >= N) return;
    int lane = threadIdx.x & 63;
    int hd = lane >> 4;
    int c0 = lane * 2;
    int off = offs[n], dg = deg[n];
    float adn = ad_[n * NH + hd];
    float pa = pql[hd * 2 + 0], qa = pql[hd * 2 + 1];

    // self-loop logit (loop attr = mean of incoming edge attrs; exactly 0 if deg==0)
    float sa = asum[n] / fmaxf((float)dg, 1.f);
    float ael = (dg > 0) ? (sa * pa + qa) : 0.f;
    float l0 = as_[n * NH + hd] + adn + ael;
    l0 = fmaxf(l0, NEG * l0);

    float mx = l0, den = 1.f;
    float2 hv = *(const float2*)(h1 + (size_t)n * DH + c0);
    float a0 = hv.x, a1 = hv.y;

    int i = 0;
    for (; i + 4 <= dg; i += 4) {
        int2 e0 = csr[off + i + 0];
        int2 e1 = csr[off + i + 1];
        int2 e2 = csr[off + i + 2];
        int2 e3 = csr[off + i + 3];
        // issue all gathers up front (4-deep MLP)
        float2 g0 = *(const float2*)(h1 + (size_t)e0.x * DH + c0);
        float2 g1 = *(const float2*)(h1 + (size_t)e1.x * DH + c0);
        float2 g2 = *(const float2*)(h1 + (size_t)e2.x * DH + c0);
        float2 g3 = *(const float2*)(h1 + (size_t)e3.x * DH + c0);
        float s0 = as_[e0.x * NH + hd];
        float s1 = as_[e1.x * NH + hd];
        float s2 = as_[e2.x * NH + hd];
        float s3 = as_[e3.x * NH + hd];
        float t0 = s0 + adn + __int_as_float(e0.y) * pa + qa;
        float t1 = s1 + adn + __int_as_float(e1.y) * pa + qa;
        float t2 = s2 + adn + __int_as_float(e2.y) * pa + qa;
        float t3 = s3 + adn + __int_as_float(e3.y) * pa + qa;
        t0 = fmaxf(t0, NEG * t0);
        t1 = fmaxf(t1, NEG * t1);
        t2 = fmaxf(t2, NEG * t2);
        t3 = fmaxf(t3, NEG * t3);
        float nm = fmaxf(fmaxf(mx, fmaxf(t0, t1)), fmaxf(t2, t3));
        float sc = __expf(mx - nm);
        float n0 = __expf(t0 - nm);
        float n1 = __expf(t1 - nm);
        float n2 = __expf(t2 - nm);
        float n3 = __expf(t3 - nm);
        den = den * sc + ((n0 + n1) + (n2 + n3));
        a0  = a0  * sc + ((n0 * g0.x + n1 * g1.x) + (n2 * g2.x + n3 * g3.x));
        a1  = a1  * sc + ((n0 * g0.y + n1 * g1.y) + (n2 * g2.y + n3 * g3.y));
        mx = nm;
    }
    for (; i < dg; ++i) {
        int2 ep = csr[off + i];
        float2 gs = *(const float2*)(h1 + (size_t)ep.x * DH + c0);
        float lg = as_[ep.x * NH + hd] + adn + __int_as_float(ep.y) * pa + qa;
        lg = fmaxf(lg, NEG * lg);
        float nm = fmaxf(mx, lg);
        float sc  = __expf(mx - nm);
        float num = __expf(lg - nm);
        den = den * sc + num;
        a0  = a0  * sc + num * gs.x;
        a1  = a1  * sc + num * gs.y;
        mx = nm;
    }
    float inv = 1.f / (den + 1e-16f);
    float o0 = a0 * inv + bias[c0];
    float o1 = a1 * inv + bias[c0 + 1];
    o0 = (o0 > 0.f) ? o0 : expm1f(o0);   // elu
    o1 = (o1 > 0.f) ? o1 : expm1f(o1);
    hout[(size_t)n * DH + c0] = o0;
    hout[(size_t)n * DH + c0 + 1] = o1;
}

// ---------------- decoder: relu(h@w1+b1)@w2+b2, fully fused ----------------
__global__ void __launch_bounds__(256) dec_kernel(
        const float* __restrict__ h, const float* __restrict__ w1,
        const float* __restrict__ b1, const float* __restrict__ w2,
        const float* __restrict__ b2, float* __restrict__ out, int N) {
    __shared__ __align__(16) float rows[32][DH];
    int tid = threadIdx.x;
    int row0 = blockIdx.x * 32;

    #pragma unroll
    for (int i = 0; i < 4; ++i) {
        int idx = tid + i * 256;
        int r = idx >> 5;
        int cq = idx & 31;
        int gr = row0 + r; if (gr > N - 1) gr = N - 1;
        ((float4*)rows[r])[cq] = ((const float4*)(h + (size_t)gr * DH))[cq];
    }
    __syncthreads();

    int wv_ = tid >> 6;
    int lane = tid & 63;
    int cg = lane & 31;
    int rh = lane >> 5;
    int rbase = wv_ * 8 + rh * 4;

    float acc[4][4];
    #pragma unroll
    for (int r = 0; r < 4; ++r)
        #pragma unroll
        for (int c = 0; c < 4; ++c) acc[r][c] = 0.f;

    #pragma unroll 2
    for (int kc = 0; kc < 32; ++kc) {
        float4 wv0 = ((const float4*)(w1 + (kc * 4 + 0) * DH))[cg];
        float4 wv1 = ((const float4*)(w1 + (kc * 4 + 1) * DH))[cg];
        float4 wv2 = ((const float4*)(w1 + (kc * 4 + 2) * DH))[cg];
        float4 wv3 = ((const float4*)(w1 + (kc * 4 + 3) * DH))[cg];
        #pragma unroll
        for (int r = 0; r < 4; ++r) {
            float4 rv = ((const float4*)rows[rbase + r])[kc];
            acc[r][0] = fmaf(rv.x, wv0.x, acc[r][0]);
            acc[r][1] = fmaf(rv.x, wv0.y, acc[r][1]);
            acc[r][2] = fmaf(rv.x, wv0.z, acc[r][2]);
            acc[r][3] = fmaf(rv.x, wv0.w, acc[r][3]);
            acc[r][0] = fmaf(rv.y, wv1.x, acc[r][0]);
            acc[r][1] = fmaf(rv.y, wv1.y, acc[r][1]);
            acc[r][2] = fmaf(rv.y, wv1.z, acc[r][2]);
            acc[r][3] = fmaf(rv.y, wv1.w, acc[r][3]);
            acc[r][0] = fmaf(rv.z, wv2.x, acc[r][0]);
            acc[r][1] = fmaf(rv.z, wv2.y, acc[r][1]);
            acc[r][2] = fmaf(rv.z, wv2.z, acc[r][2]);
            acc[r][3] = fmaf(rv.z, wv2.w, acc[r][3]);
            acc[r][0] = fmaf(rv.w, wv3.x, acc[r][0]);
            acc[r][1] = fmaf(rv.w, wv3.y, acc[r][1]);
            acc[r][2] = fmaf(rv.w, wv3.z, acc[r][2]);
            acc[r][3] = fmaf(rv.w, wv3.w, acc[r][3]);
        }
    }

    // epilogue: relu + project to 2 outputs; each half-wave covers all 128 cols
    float4 b14 = ((const float4*)b1)[cg];
    float4 wA = ((const float4*)w2)[cg * 2 + 0];   // {c0p0,c0p1,c1p0,c1p1}
    float4 wB = ((const float4*)w2)[cg * 2 + 1];   // {c2p0,c2p1,c3p0,c3p1}
    float bb0 = b2[0], bb1 = b2[1];
    #pragma unroll
    for (int r = 0; r < 4; ++r) {
        float h0 = fmaxf(acc[r][0] + b14.x, 0.f);
        float h1v = fmaxf(acc[r][1] + b14.y, 0.f);
        float h2 = fmaxf(acc[r][2] + b14.z, 0.f);
        float h3 = fmaxf(acc[r][3] + b14.w, 0.f);
        float p0 = h0 * wA.x + h1v * wA.z + h2 * wB.x + h3 * wB.z;
        float p1 = h0 * wA.y + h1v * wA.w + h2 * wB.y + h3 * wB.w;
        #pragma unroll
        for (int o = 16; o > 0; o >>= 1) {
            p0 += __shfl_down(p0, o, 32);
            p1 += __shfl_down(p1, o, 32);
        }
        int row = row0 + rbase + r;
        if (cg == 0 && row < N) {
            out[row * 2 + 0] = p0 + bb0;
            out[row * 2 + 1] = p1 + bb1;
        }
    }
}

extern "C" void kernel_launch(void* const* d_in, const int* in_sizes, int n_in,
                              void* d_out, int out_size, void* d_ws, size_t ws_size,
                              hipStream_t stream) {
    const float* x          = (const float*)d_in[0];
    const int*   ei         = (const int*)d_in[1];
    const float* eattr      = (const float*)d_in[2];
    const float* enc_node_w = (const float*)d_in[3];
    const float* enc_node_b = (const float*)d_in[4];
    const float* enc_edge_w = (const float*)d_in[5];
    const float* enc_edge_b = (const float*)d_in[6];
    const float* lin_w      = (const float*)d_in[7];
    const float* lin_edge_w = (const float*)d_in[8];
    const float* att_src    = (const float*)d_in[9];
    const float* att_dst    = (const float*)d_in[10];
    const float* att_edge   = (const float*)d_in[11];
    const float* gat_bias   = (const float*)d_in[12];
    const float* dec_w1     = (const float*)d_in[13];
    const float* dec_b1     = (const float*)d_in[14];
    const float* dec_w2     = (const float*)d_in[15];
    const float* dec_b2     = (const float*)d_in[16];

    const int E = in_sizes[2];          // DE == 1
    const int N = in_sizes[0] / DIN;

    char* w = (char*)d_ws;
    auto alloc = [&](size_t bytes) -> void* {
        void* p = (void*)w;
        w += (bytes + 511) & ~((size_t)511);
        return p;
    };
    float* h      = (float*)alloc((size_t)N * DH * 4);
    float* h1     = (float*)alloc((size_t)N * DH * 4);
    float* as_    = (float*)alloc((size_t)N * NH * 4);
    float* ad_    = (float*)alloc((size_t)N * NH * 4);
    int*   deg    = (int*)alloc((size_t)N * 4);
    float* asum   = (float*)alloc((size_t)N * 4);
    int*   offs   = (int*)alloc((size_t)N * 4);
    int*   cursor = (int*)alloc((size_t)N * 4);
    int*   bsum   = (int*)alloc(64 * 4);
    int*   boff   = (int*)alloc(64 * 4);
    int2*  csr    = (int2*)alloc((size_t)E * 8);
    float* pq     = (float*)alloc(NL * NH * 2 * 4);

    hipMemsetAsync(deg, 0, (size_t)N * 4, stream);
    hipMemsetAsync(asum, 0, (size_t)N * 4, stream);

    pq_kernel<<<NL * NH, 64, 0, stream>>>(enc_edge_w, enc_edge_b, lin_edge_w, att_edge, pq);
    enc_kernel<<<(N + 31) / 32, 256, 0, stream>>>(x, enc_node_w, enc_node_b, h, N);
    deg_kernel<<<(E + 255) / 256, 256, 0, stream>>>(ei, eattr, deg, asum, E);

    int nb = (N + 1023) / 1024;
    scan1<<<nb, 1024, 0, stream>>>(deg, offs, bsum, N);
    scan2<<<1, 64, 0, stream>>>(bsum, boff, nb);
    scan3<<<nb, 1024, 0, stream>>>(offs, cursor, boff, N);
    scatter_kernel<<<(E + 255) / 256, 256, 0, stream>>>(ei, eattr, cursor, csr, E);

    for (int l = 0; l < NL; ++l) {
        layer_node<<<(N + 31) / 32, 256, 0, stream>>>(h, lin_w + (size_t)l * DH * DH,
                                                      att_src + l * DH, att_dst + l * DH,
                                                      h1, as_, ad_, N);
        agg_kernel<<<(N + 3) / 4, 256, 0, stream>>>(h1, as_, ad_, offs, deg, asum, csr,
                                                    pq + l * NH * 2, gat_bias + l * DH, h, N);
    }
    dec_kernel<<<(N + 31) / 32, 256, 0, stream>>>(h, dec_w1, dec_b1, dec_w2, dec_b2,
                                                  (float*)d_out, N);
}

// Round 6
// 456.241 us; speedup vs baseline: 1.8747x; 1.1053x over previous
//
#include <hip/hip_runtime.h>
#include <math.h>

#define DIN 17
#define DH  128
#define NH  4
#define CC  32
#define NL  3
#define NEG 0.2f

// packed CSR-build constants: pk[d] = (count << 44) | sum_fixed
// sum_fixed accumulates (a + 16.0) * 2^20 per edge (always positive, < 2^26)
#define PK_SHIFT 44
#define PK_MASK  ((1ULL << PK_SHIFT) - 1)
#define PK_BIAS  16.0f
#define PK_SCALE 1048576.0f   // 2^20

// ---------------- tiny per-layer edge-projection scalars ----------------
__global__ void pq_kernel(const float* __restrict__ ew, const float* __restrict__ eb,
                          const float* __restrict__ We, const float* __restrict__ ae,
                          float* __restrict__ pq) {
    int lh = blockIdx.x;            // 0..11
    int l = lh >> 2, h = lh & 3;
    int t = threadIdx.x;            // 64
    const float* Wel = We + l * DH * DH;
    const float* ael = ae + l * DH + h * CC;
    float p = 0.f, q = 0.f;
    for (int d = t; d < DH; d += 64) {
        const float* row = Wel + d * DH + h * CC;
        float wp = 0.f;
        for (int c = 0; c < CC; ++c) wp += row[c] * ael[c];
        p += ew[d] * wp;
        q += eb[d] * wp;
    }
    for (int o = 32; o > 0; o >>= 1) { p += __shfl_down(p, o, 64); q += __shfl_down(q, o, 64); }
    if (t == 0) { pq[lh * 2 + 0] = p; pq[lh * 2 + 1] = q; }
}

// ---------------- node encoder: h = x @ Wn + bn (32 rows/block) ----------------
__global__ void enc_kernel(const float* __restrict__ x, const float* __restrict__ W,
                           const float* __restrict__ b, float* __restrict__ h, int N) {
    __shared__ float wl[DIN][DH];
    __shared__ float xs[32][DIN];
    int tid = threadIdx.x;          // 256
    int row0 = blockIdx.x * 32;
    for (int i = tid; i < DIN * DH; i += 256) wl[i / DH][i % DH] = W[i];
    for (int i = tid; i < 32 * DIN; i += 256) {
        int r = i / DIN, k = i % DIN;
        int rr = row0 + r; if (rr > N - 1) rr = N - 1;
        xs[r][k] = x[(size_t)rr * DIN + k];
    }
    __syncthreads();
    int c = tid & 127;
    int g = tid >> 7;
    float bias = b[c];
    #pragma unroll
    for (int r = 0; r < 16; ++r) {
        int row = row0 + g * 16 + r;
        if (row >= N) break;
        float acc = bias;
        #pragma unroll
        for (int k = 0; k < DIN; ++k) acc += xs[g * 16 + r][k] * wl[k][c];
        h[(size_t)row * DH + c] = acc;
    }
}

// ---------------- per-layer node transform: h1 = h@W + fused att reductions ----------
__global__ void __launch_bounds__(256) layer_node(
        const float* __restrict__ h, const float* __restrict__ W,
        const float* __restrict__ asv, const float* __restrict__ adv,
        float* __restrict__ h1, float* __restrict__ as_, float* __restrict__ ad_,
        int N) {
    __shared__ __align__(16) float rows[32][DH];
    int tid = threadIdx.x;
    int row0 = blockIdx.x * 32;

    #pragma unroll
    for (int i = 0; i < 4; ++i) {
        int idx = tid + i * 256;        // float4 index 0..1023
        int r = idx >> 5;               // 32 float4 per row
        int cq = idx & 31;
        int gr = row0 + r; if (gr > N - 1) gr = N - 1;
        ((float4*)rows[r])[cq] = ((const float4*)(h + (size_t)gr * DH))[cq];
    }
    __syncthreads();

    int wv_ = tid >> 6;                 // wave 0..3
    int lane = tid & 63;
    int cg = lane & 31;                 // col group: cols cg*4..cg*4+3
    int rh = lane >> 5;                 // row half within wave
    int rbase = wv_ * 8 + rh * 4;       // 4 rows: rbase..rbase+3

    float acc[4][4];
    #pragma unroll
    for (int r = 0; r < 4; ++r)
        #pragma unroll
        for (int c = 0; c < 4; ++c) acc[r][c] = 0.f;

    #pragma unroll 2
    for (int kc = 0; kc < 32; ++kc) {   // K chunks of 4
        float4 wv0 = ((const float4*)(W + (kc * 4 + 0) * DH))[cg];
        float4 wv1 = ((const float4*)(W + (kc * 4 + 1) * DH))[cg];
        float4 wv2 = ((const float4*)(W + (kc * 4 + 2) * DH))[cg];
        float4 wv3 = ((const float4*)(W + (kc * 4 + 3) * DH))[cg];
        #pragma unroll
        for (int r = 0; r < 4; ++r) {
            float4 rv = ((const float4*)rows[rbase + r])[kc];
            acc[r][0] = fmaf(rv.x, wv0.x, acc[r][0]);
            acc[r][1] = fmaf(rv.x, wv0.y, acc[r][1]);
            acc[r][2] = fmaf(rv.x, wv0.z, acc[r][2]);
            acc[r][3] = fmaf(rv.x, wv0.w, acc[r][3]);
            acc[r][0] = fmaf(rv.y, wv1.x, acc[r][0]);
            acc[r][1] = fmaf(rv.y, wv1.y, acc[r][1]);
            acc[r][2] = fmaf(rv.y, wv1.z, acc[r][2]);
            acc[r][3] = fmaf(rv.y, wv1.w, acc[r][3]);
            acc[r][0] = fmaf(rv.z, wv2.x, acc[r][0]);
            acc[r][1] = fmaf(rv.z, wv2.y, acc[r][1]);
            acc[r][2] = fmaf(rv.z, wv2.z, acc[r][2]);
            acc[r][3] = fmaf(rv.z, wv2.w, acc[r][3]);
            acc[r][0] = fmaf(rv.w, wv3.x, acc[r][0]);
            acc[r][1] = fmaf(rv.w, wv3.y, acc[r][1]);
            acc[r][2] = fmaf(rv.w, wv3.z, acc[r][2]);
            acc[r][3] = fmaf(rv.w, wv3.w, acc[r][3]);
        }
    }

    float4 as4 = ((const float4*)asv)[cg];
    float4 ad4 = ((const float4*)adv)[cg];
    int head = cg >> 3;
    #pragma unroll
    for (int r = 0; r < 4; ++r) {
        int row = row0 + rbase + r;
        bool valid = row < N;
        if (valid) {
            float4 o; o.x = acc[r][0]; o.y = acc[r][1]; o.z = acc[r][2]; o.w = acc[r][3];
            ((float4*)(h1 + (size_t)row * DH))[cg] = o;
        }
        float ps = acc[r][0] * as4.x + acc[r][1] * as4.y + acc[r][2] * as4.z + acc[r][3] * as4.w;
        float pd = acc[r][0] * ad4.x + acc[r][1] * ad4.y + acc[r][2] * ad4.z + acc[r][3] * ad4.w;
        #pragma unroll
        for (int o = 4; o > 0; o >>= 1) {
            ps += __shfl_down(ps, o, 8);
            pd += __shfl_down(pd, o, 8);
        }
        if (valid && (lane & 7) == 0) {
            as_[row * NH + head] = ps;
            ad_[row * NH + head] = pd;
        }
    }
}

// ---------------- phase 1: packed {count|attr-sum} atomic; records per-edge rank ---
__global__ void rank_kernel(const int* __restrict__ ei, const float* __restrict__ ea,
                            unsigned long long* __restrict__ pk, int* __restrict__ rank,
                            int E) {
    int e = blockIdx.x * 256 + threadIdx.x;
    if (e >= E) return;
    int d = ei[E + e];
    unsigned long long enc = (1ULL << PK_SHIFT) |
        (unsigned long long)(int)((ea[e] + PK_BIAS) * PK_SCALE);
    unsigned long long old = atomicAdd(&pk[d], enc);
    rank[e] = (int)(old >> PK_SHIFT);
}

// ---------------- 3-kernel exclusive scan over packed counts ----------------
__global__ void scan1(const unsigned long long* __restrict__ pk, int* __restrict__ offs,
                      int* __restrict__ bsum, int N) {
    __shared__ int buf[1024];
    int b = blockIdx.x, t = threadIdx.x, i = b * 1024 + t;
    int v = (i < N) ? (int)(pk[i] >> PK_SHIFT) : 0;
    buf[t] = v;
    __syncthreads();
    int val = v;
    for (int o = 1; o < 1024; o <<= 1) {
        int add = (t >= o) ? buf[t - o] : 0;
        __syncthreads();
        val += add;
        buf[t] = val;
        __syncthreads();
    }
    if (i < N) offs[i] = val - v;
    if (t == 1023) bsum[b] = val;
}

__global__ void scan2(const int* __restrict__ bsum, int* __restrict__ boff, int nb) {
    if (threadIdx.x == 0) {
        int s = 0;
        for (int b = 0; b < nb; ++b) { boff[b] = s; s += bsum[b]; }
    }
}

// finalize offsets + unpack deg/asum
__global__ void scan3(int* __restrict__ offs, const int* __restrict__ boff,
                      const unsigned long long* __restrict__ pk,
                      int* __restrict__ deg, float* __restrict__ asum, int N) {
    int i = blockIdx.x * 1024 + threadIdx.x;
    if (i >= N) return;
    offs[i] += boff[blockIdx.x];
    unsigned long long p = pk[i];
    int cnt = (int)(p >> PK_SHIFT);
    float s = (float)(p & PK_MASK) * (1.0f / PK_SCALE) - (float)cnt * PK_BIAS;
    deg[i] = cnt;
    asum[i] = s;
}

// ---------------- phase 2: atomic-free scatter into CSR ----------------
__global__ void scatter_kernel(const int* __restrict__ ei, const float* __restrict__ ea,
                               const int* __restrict__ offs, const int* __restrict__ rank,
                               int2* __restrict__ csr, int E) {
    int e = blockIdx.x * 256 + threadIdx.x;
    if (e >= E) return;
    int d = ei[E + e];
    int pos = offs[d] + rank[e];
    int2 p; p.x = ei[e]; p.y = __float_as_int(ea[e]);
    csr[pos] = p;
}

// ---------------- per-node attention + aggregation: no-max softmax, unroll-4 ------
// softmax is shift-invariant; logits here are bounded << 88 so exp() cannot
// overflow fp32 — dropping the running max removes the serial rescale chain.
__global__ void __launch_bounds__(256) agg_kernel(
        const float* __restrict__ h1, const float* __restrict__ as_,
        const float* __restrict__ ad_, const int* __restrict__ offs,
        const int* __restrict__ deg, const float* __restrict__ asum,
        const int2* __restrict__ csr,
        const float* __restrict__ pql, const float* __restrict__ bias,
        float* __restrict__ hout, int N) {
    int n = blockIdx.x * 4 + (threadIdx.x >> 6);
    if (n >= N) return;
    int lane = threadIdx.x & 63;
    int hd = lane >> 4;
    int c0 = lane * 2;
    int off = offs[n], dg = deg[n];
    float adn = ad_[n * NH + hd];
    float pa = pql[hd * 2 + 0], qa = pql[hd * 2 + 1];

    // self-loop logit (loop attr = mean of incoming edge attrs; exactly 0 if deg==0)
    float sa = asum[n] / fmaxf((float)dg, 1.f);
    float ael = (dg > 0) ? (sa * pa + qa) : 0.f;
    float l0 = as_[n * NH + hd] + adn + ael;
    l0 = fmaxf(l0, NEG * l0);

    float2 hv = *(const float2*)(h1 + (size_t)n * DH + c0);
    float numS = __expf(l0);
    // two independent accumulator sets to break the add dependency
    float denA = numS, a0A = numS * hv.x, a1A = numS * hv.y;
    float denB = 0.f,  a0B = 0.f,         a1B = 0.f;

    int i = 0;
    for (; i + 4 <= dg; i += 4) {
        int2 e0 = csr[off + i + 0];
        int2 e1 = csr[off + i + 1];
        int2 e2 = csr[off + i + 2];
        int2 e3 = csr[off + i + 3];
        float2 g0 = *(const float2*)(h1 + (size_t)e0.x * DH + c0);
        float2 g1 = *(const float2*)(h1 + (size_t)e1.x * DH + c0);
        float2 g2 = *(const float2*)(h1 + (size_t)e2.x * DH + c0);
        float2 g3 = *(const float2*)(h1 + (size_t)e3.x * DH + c0);
        float s0 = as_[e0.x * NH + hd];
        float s1 = as_[e1.x * NH + hd];
        float s2 = as_[e2.x * NH + hd];
        float s3 = as_[e3.x * NH + hd];
        float t0 = s0 + adn + __int_as_float(e0.y) * pa + qa;
        float t1 = s1 + adn + __int_as_float(e1.y) * pa + qa;
        float t2 = s2 + adn + __int_as_float(e2.y) * pa + qa;
        float t3 = s3 + adn + __int_as_float(e3.y) * pa + qa;
        t0 = fmaxf(t0, NEG * t0);
        t1 = fmaxf(t1, NEG * t1);
        t2 = fmaxf(t2, NEG * t2);
        t3 = fmaxf(t3, NEG * t3);
        float n0 = __expf(t0);
        float n1 = __expf(t1);
        float n2 = __expf(t2);
        float n3 = __expf(t3);
        denA += n0 + n2; denB += n1 + n3;
        a0A = fmaf(n0, g0.x, a0A); a0B = fmaf(n1, g1.x, a0B);
        a0A = fmaf(n2, g2.x, a0A); a0B = fmaf(n3, g3.x, a0B);
        a1A = fmaf(n0, g0.y, a1A); a1B = fmaf(n1, g1.y, a1B);
        a1A = fmaf(n2, g2.y, a1A); a1B = fmaf(n3, g3.y, a1B);
    }
    for (; i < dg; ++i) {
        int2 ep = csr[off + i];
        float2 gs = *(const float2*)(h1 + (size_t)ep.x * DH + c0);
        float lg = as_[ep.x * NH + hd] + adn + __int_as_float(ep.y) * pa + qa;
        lg = fmaxf(lg, NEG * lg);
        float num = __expf(lg);
        denA += num;
        a0A = fmaf(num, gs.x, a0A);
        a1A = fmaf(num, gs.y, a1A);
    }
    float den = denA + denB;
    float a0 = a0A + a0B, a1 = a1A + a1B;
    float inv = 1.f / (den + 1e-16f);
    float o0 = a0 * inv + bias[c0];
    float o1 = a1 * inv + bias[c0 + 1];
    o0 = (o0 > 0.f) ? o0 : expm1f(o0);   // elu
    o1 = (o1 > 0.f) ? o1 : expm1f(o1);
    hout[(size_t)n * DH + c0] = o0;
    hout[(size_t)n * DH + c0 + 1] = o1;
}

// ---------------- decoder: relu(h@w1+b1)@w2+b2, fully fused ----------------
__global__ void __launch_bounds__(256) dec_kernel(
        const float* __restrict__ h, const float* __restrict__ w1,
        const float* __restrict__ b1, const float* __restrict__ w2,
        const float* __restrict__ b2, float* __restrict__ out, int N) {
    __shared__ __align__(16) float rows[32][DH];
    int tid = threadIdx.x;
    int row0 = blockIdx.x * 32;

    #pragma unroll
    for (int i = 0; i < 4; ++i) {
        int idx = tid + i * 256;
        int r = idx >> 5;
        int cq = idx & 31;
        int gr = row0 + r; if (gr > N - 1) gr = N - 1;
        ((float4*)rows[r])[cq] = ((const float4*)(h + (size_t)gr * DH))[cq];
    }
    __syncthreads();

    int wv_ = tid >> 6;
    int lane = tid & 63;
    int cg = lane & 31;
    int rh = lane >> 5;
    int rbase = wv_ * 8 + rh * 4;

    float acc[4][4];
    #pragma unroll
    for (int r = 0; r < 4; ++r)
        #pragma unroll
        for (int c = 0; c < 4; ++c) acc[r][c] = 0.f;

    #pragma unroll 2
    for (int kc = 0; kc < 32; ++kc) {
        float4 wv0 = ((const float4*)(w1 + (kc * 4 + 0) * DH))[cg];
        float4 wv1 = ((const float4*)(w1 + (kc * 4 + 1) * DH))[cg];
        float4 wv2 = ((const float4*)(w1 + (kc * 4 + 2) * DH))[cg];
        float4 wv3 = ((const float4*)(w1 + (kc * 4 + 3) * DH))[cg];
        #pragma unroll
        for (int r = 0; r < 4; ++r) {
            float4 rv = ((const float4*)rows[rbase + r])[kc];
            acc[r][0] = fmaf(rv.x, wv0.x, acc[r][0]);
            acc[r][1] = fmaf(rv.x, wv0.y, acc[r][1]);
            acc[r][2] = fmaf(rv.x, wv0.z, acc[r][2]);
            acc[r][3] = fmaf(rv.x, wv0.w, acc[r][3]);
            acc[r][0] = fmaf(rv.y, wv1.x, acc[r][0]);
            acc[r][1] = fmaf(rv.y, wv1.y, acc[r][1]);
            acc[r][2] = fmaf(rv.y, wv1.z, acc[r][2]);
            acc[r][3] = fmaf(rv.y, wv1.w, acc[r][3]);
            acc[r][0] = fmaf(rv.z, wv2.x, acc[r][0]);
            acc[r][1] = fmaf(rv.z, wv2.y, acc[r][1]);
            acc[r][2] = fmaf(rv.z, wv2.z, acc[r][2]);
            acc[r][3] = fmaf(rv.z, wv2.w, acc[r][3]);
            acc[r][0] = fmaf(rv.w, wv3.x, acc[r][0]);
            acc[r][1] = fmaf(rv.w, wv3.y, acc[r][1]);
            acc[r][2] = fmaf(rv.w, wv3.z, acc[r][2]);
            acc[r][3] = fmaf(rv.w, wv3.w, acc[r][3]);
        }
    }

    float4 b14 = ((const float4*)b1)[cg];
    float4 wA = ((const float4*)w2)[cg * 2 + 0];
    float4 wB = ((const float4*)w2)[cg * 2 + 1];
    float bb0 = b2[0], bb1 = b2[1];
    #pragma unroll
    for (int r = 0; r < 4; ++r) {
        float h0 = fmaxf(acc[r][0] + b14.x, 0.f);
        float h1v = fmaxf(acc[r][1] + b14.y, 0.f);
        float h2 = fmaxf(acc[r][2] + b14.z, 0.f);
        float h3 = fmaxf(acc[r][3] + b14.w, 0.f);
        float p0 = h0 * wA.x + h1v * wA.z + h2 * wB.x + h3 * wB.z;
        float p1 = h0 * wA.y + h1v * wA.w + h2 * wB.y + h3 * wB.w;
        #pragma unroll
        for (int o = 16; o > 0; o >>= 1) {
            p0 += __shfl_down(p0, o, 32);
            p1 += __shfl_down(p1, o, 32);
        }
        int row = row0 + rbase + r;
        if (cg == 0 && row < N) {
            out[row * 2 + 0] = p0 + bb0;
            out[row * 2 + 1] = p1 + bb1;
        }
    }
}

extern "C" void kernel_launch(void* const* d_in, const int* in_sizes, int n_in,
                              void* d_out, int out_size, void* d_ws, size_t ws_size,
                              hipStream_t stream) {
    const float* x          = (const float*)d_in[0];
    const int*   ei         = (const int*)d_in[1];
    const float* eattr      = (const float*)d_in[2];
    const float* enc_node_w = (const float*)d_in[3];
    const float* enc_node_b = (const float*)d_in[4];
    const float* enc_edge_w = (const float*)d_in[5];
    const float* enc_edge_b = (const float*)d_in[6];
    const float* lin_w      = (const float*)d_in[7];
    const float* lin_edge_w = (const float*)d_in[8];
    const float* att_src    = (const float*)d_in[9];
    const float* att_dst    = (const float*)d_in[10];
    const float* att_edge   = (const float*)d_in[11];
    const float* gat_bias   = (const float*)d_in[12];
    const float* dec_w1     = (const float*)d_in[13];
    const float* dec_b1     = (const float*)d_in[14];
    const float* dec_w2     = (const float*)d_in[15];
    const float* dec_b2     = (const float*)d_in[16];

    const int E = in_sizes[2];          // DE == 1
    const int N = in_sizes[0] / DIN;

    char* w = (char*)d_ws;
    auto alloc = [&](size_t bytes) -> void* {
        void* p = (void*)w;
        w += (bytes + 511) & ~((size_t)511);
        return p;
    };
    float* h      = (float*)alloc((size_t)N * DH * 4);
    float* h1     = (float*)alloc((size_t)N * DH * 4);
    float* as_    = (float*)alloc((size_t)N * NH * 4);
    float* ad_    = (float*)alloc((size_t)N * NH * 4);
    unsigned long long* pk = (unsigned long long*)alloc((size_t)N * 8);
    int*   rank   = (int*)alloc((size_t)E * 4);
    int*   deg    = (int*)alloc((size_t)N * 4);
    float* asum   = (float*)alloc((size_t)N * 4);
    int*   offs   = (int*)alloc((size_t)N * 4);
    int*   bsum   = (int*)alloc(64 * 4);
    int*   boff   = (int*)alloc(64 * 4);
    int2*  csr    = (int2*)alloc((size_t)E * 8);
    float* pq     = (float*)alloc(NL * NH * 2 * 4);

    hipMemsetAsync(pk, 0, (size_t)N * 8, stream);

    pq_kernel<<<NL * NH, 64, 0, stream>>>(enc_edge_w, enc_edge_b, lin_edge_w, att_edge, pq);
    enc_kernel<<<(N + 31) / 32, 256, 0, stream>>>(x, enc_node_w, enc_node_b, h, N);
    rank_kernel<<<(E + 255) / 256, 256, 0, stream>>>(ei, eattr, pk, rank, E);

    int nb = (N + 1023) / 1024;
    scan1<<<nb, 1024, 0, stream>>>(pk, offs, bsum, N);
    scan2<<<1, 64, 0, stream>>>(bsum, boff, nb);
    scan3<<<nb, 1024, 0, stream>>>(offs, boff, pk, deg, asum, N);
    scatter_kernel<<<(E + 255) / 256, 256, 0, stream>>>(ei, eattr, offs, rank, csr, E);

    for (int l = 0; l < NL; ++l) {
        layer_node<<<(N + 31) / 32, 256, 0, stream>>>(h, lin_w + (size_t)l * DH * DH,
                                                      att_src + l * DH, att_dst + l * DH,
                                                      h1, as_, ad_, N);
        agg_kernel<<<(N + 3) / 4, 256, 0, stream>>>(h1, as_, ad_, offs, deg, asum, csr,
                                                    pq + l * NH * 2, gat_bias + l * DH, h, N);
    }
    dec_kernel<<<(N + 31) / 32, 256, 0, stream>>>(h, dec_w1, dec_b1, dec_w2, dec_b2,
                                                  (float*)d_out, N);
}

// Round 7
// 411.559 us; speedup vs baseline: 2.0782x; 1.1086x over previous
//
#include <hip/hip_runtime.h>
#include <hip/hip_fp16.h>
#include <math.h>

#define DIN 17
#define DH  128
#define NH  4
#define CC  32
#define NL  3
#define NEG 0.2f

// packed CSR-build constants: pk[d] = (count << 44) | sum_fixed
#define PK_SHIFT 44
#define PK_MASK  ((1ULL << PK_SHIFT) - 1)
#define PK_BIAS  16.0f
#define PK_SCALE 1048576.0f   // 2^20

// ---------------- tiny per-layer edge-projection scalars ----------------
__global__ void pq_kernel(const float* __restrict__ ew, const float* __restrict__ eb,
                          const float* __restrict__ We, const float* __restrict__ ae,
                          float* __restrict__ pq) {
    int lh = blockIdx.x;            // 0..11
    int l = lh >> 2, h = lh & 3;
    int t = threadIdx.x;            // 64
    const float* Wel = We + l * DH * DH;
    const float* ael = ae + l * DH + h * CC;
    float p = 0.f, q = 0.f;
    for (int d = t; d < DH; d += 64) {
        const float* row = Wel + d * DH + h * CC;
        float wp = 0.f;
        for (int c = 0; c < CC; ++c) wp += row[c] * ael[c];
        p += ew[d] * wp;
        q += eb[d] * wp;
    }
    for (int o = 32; o > 0; o >>= 1) { p += __shfl_down(p, o, 64); q += __shfl_down(q, o, 64); }
    if (t == 0) { pq[lh * 2 + 0] = p; pq[lh * 2 + 1] = q; }
}

// ---------------- node encoder: h = x @ Wn + bn (32 rows/block) ----------------
__global__ void enc_kernel(const float* __restrict__ x, const float* __restrict__ W,
                           const float* __restrict__ b, float* __restrict__ h, int N) {
    __shared__ float wl[DIN][DH];
    __shared__ float xs[32][DIN];
    int tid = threadIdx.x;          // 256
    int row0 = blockIdx.x * 32;
    for (int i = tid; i < DIN * DH; i += 256) wl[i / DH][i % DH] = W[i];
    for (int i = tid; i < 32 * DIN; i += 256) {
        int r = i / DIN, k = i % DIN;
        int rr = row0 + r; if (rr > N - 1) rr = N - 1;
        xs[r][k] = x[(size_t)rr * DIN + k];
    }
    __syncthreads();
    int c = tid & 127;
    int g = tid >> 7;
    float bias = b[c];
    #pragma unroll
    for (int r = 0; r < 16; ++r) {
        int row = row0 + g * 16 + r;
        if (row >= N) break;
        float acc = bias;
        #pragma unroll
        for (int k = 0; k < DIN; ++k) acc += xs[g * 16 + r][k] * wl[k][c];
        h[(size_t)row * DH + c] = acc;
    }
}

// ---------------- per-layer node transform: h1h(fp16) = h@W + fused att reductions --
__global__ void __launch_bounds__(256) layer_node(
        const float* __restrict__ h, const float* __restrict__ W,
        const float* __restrict__ asv, const float* __restrict__ adv,
        __half* __restrict__ h1h, float* __restrict__ as_, float* __restrict__ ad_,
        int N) {
    __shared__ __align__(16) float rows[32][DH];
    int tid = threadIdx.x;
    int row0 = blockIdx.x * 32;

    #pragma unroll
    for (int i = 0; i < 4; ++i) {
        int idx = tid + i * 256;        // float4 index 0..1023
        int r = idx >> 5;               // 32 float4 per row
        int cq = idx & 31;
        int gr = row0 + r; if (gr > N - 1) gr = N - 1;
        ((float4*)rows[r])[cq] = ((const float4*)(h + (size_t)gr * DH))[cq];
    }
    __syncthreads();

    int wv_ = tid >> 6;                 // wave 0..3
    int lane = tid & 63;
    int cg = lane & 31;                 // col group: cols cg*4..cg*4+3
    int rh = lane >> 5;                 // row half within wave
    int rbase = wv_ * 8 + rh * 4;       // 4 rows: rbase..rbase+3

    float acc[4][4];
    #pragma unroll
    for (int r = 0; r < 4; ++r)
        #pragma unroll
        for (int c = 0; c < 4; ++c) acc[r][c] = 0.f;

    #pragma unroll 2
    for (int kc = 0; kc < 32; ++kc) {   // K chunks of 4
        float4 wv0 = ((const float4*)(W + (kc * 4 + 0) * DH))[cg];
        float4 wv1 = ((const float4*)(W + (kc * 4 + 1) * DH))[cg];
        float4 wv2 = ((const float4*)(W + (kc * 4 + 2) * DH))[cg];
        float4 wv3 = ((const float4*)(W + (kc * 4 + 3) * DH))[cg];
        #pragma unroll
        for (int r = 0; r < 4; ++r) {
            float4 rv = ((const float4*)rows[rbase + r])[kc];
            acc[r][0] = fmaf(rv.x, wv0.x, acc[r][0]);
            acc[r][1] = fmaf(rv.x, wv0.y, acc[r][1]);
            acc[r][2] = fmaf(rv.x, wv0.z, acc[r][2]);
            acc[r][3] = fmaf(rv.x, wv0.w, acc[r][3]);
            acc[r][0] = fmaf(rv.y, wv1.x, acc[r][0]);
            acc[r][1] = fmaf(rv.y, wv1.y, acc[r][1]);
            acc[r][2] = fmaf(rv.y, wv1.z, acc[r][2]);
            acc[r][3] = fmaf(rv.y, wv1.w, acc[r][3]);
            acc[r][0] = fmaf(rv.z, wv2.x, acc[r][0]);
            acc[r][1] = fmaf(rv.z, wv2.y, acc[r][1]);
            acc[r][2] = fmaf(rv.z, wv2.z, acc[r][2]);
            acc[r][3] = fmaf(rv.z, wv2.w, acc[r][3]);
            acc[r][0] = fmaf(rv.w, wv3.x, acc[r][0]);
            acc[r][1] = fmaf(rv.w, wv3.y, acc[r][1]);
            acc[r][2] = fmaf(rv.w, wv3.z, acc[r][2]);
            acc[r][3] = fmaf(rv.w, wv3.w, acc[r][3]);
        }
    }

    float4 as4 = ((const float4*)asv)[cg];
    float4 ad4 = ((const float4*)adv)[cg];
    int head = cg >> 3;
    #pragma unroll
    for (int r = 0; r < 4; ++r) {
        int row = row0 + rbase + r;
        bool valid = row < N;
        if (valid) {
            union { __half2 h2[2]; uint2 u; } pk2;
            pk2.h2[0] = __floats2half2_rn(acc[r][0], acc[r][1]);
            pk2.h2[1] = __floats2half2_rn(acc[r][2], acc[r][3]);
            ((uint2*)(h1h + (size_t)row * DH))[cg] = pk2.u;
        }
        float ps = acc[r][0] * as4.x + acc[r][1] * as4.y + acc[r][2] * as4.z + acc[r][3] * as4.w;
        float pd = acc[r][0] * ad4.x + acc[r][1] * ad4.y + acc[r][2] * ad4.z + acc[r][3] * ad4.w;
        #pragma unroll
        for (int o = 4; o > 0; o >>= 1) {
            ps += __shfl_down(ps, o, 8);
            pd += __shfl_down(pd, o, 8);
        }
        if (valid && (lane & 7) == 0) {
            as_[row * NH + head] = ps;
            ad_[row * NH + head] = pd;
        }
    }
}

// ---------------- phase 1: packed {count|attr-sum} atomic; records per-edge rank ---
__global__ void rank_kernel(const int* __restrict__ ei, const float* __restrict__ ea,
                            unsigned long long* __restrict__ pk, int* __restrict__ rank,
                            int E) {
    int e = blockIdx.x * 256 + threadIdx.x;
    if (e >= E) return;
    int d = ei[E + e];
    unsigned long long enc = (1ULL << PK_SHIFT) |
        (unsigned long long)(int)((ea[e] + PK_BIAS) * PK_SCALE);
    unsigned long long old = atomicAdd(&pk[d], enc);
    rank[e] = (int)(old >> PK_SHIFT);
}

// ---------------- 3-kernel exclusive scan over packed counts ----------------
__global__ void scan1(const unsigned long long* __restrict__ pk, int* __restrict__ offs,
                      int* __restrict__ bsum, int N) {
    __shared__ int buf[1024];
    int b = blockIdx.x, t = threadIdx.x, i = b * 1024 + t;
    int v = (i < N) ? (int)(pk[i] >> PK_SHIFT) : 0;
    buf[t] = v;
    __syncthreads();
    int val = v;
    for (int o = 1; o < 1024; o <<= 1) {
        int add = (t >= o) ? buf[t - o] : 0;
        __syncthreads();
        val += add;
        buf[t] = val;
        __syncthreads();
    }
    if (i < N) offs[i] = val - v;
    if (t == 1023) bsum[b] = val;
}

__global__ void scan2(const int* __restrict__ bsum, int* __restrict__ boff, int nb) {
    if (threadIdx.x == 0) {
        int s = 0;
        for (int b = 0; b < nb; ++b) { boff[b] = s; s += bsum[b]; }
    }
}

// finalize offsets + unpack deg/asum
__global__ void scan3(int* __restrict__ offs, const int* __restrict__ boff,
                      const unsigned long long* __restrict__ pk,
                      int* __restrict__ deg, float* __restrict__ asum, int N) {
    int i = blockIdx.x * 1024 + threadIdx.x;
    if (i >= N) return;
    offs[i] += boff[blockIdx.x];
    unsigned long long p = pk[i];
    int cnt = (int)(p >> PK_SHIFT);
    float s = (float)(p & PK_MASK) * (1.0f / PK_SCALE) - (float)cnt * PK_BIAS;
    deg[i] = cnt;
    asum[i] = s;
}

// ---------------- phase 2: atomic-free scatter into CSR ----------------
__global__ void scatter_kernel(const int* __restrict__ ei, const float* __restrict__ ea,
                               const int* __restrict__ offs, const int* __restrict__ rank,
                               int2* __restrict__ csr, int E) {
    int e = blockIdx.x * 256 + threadIdx.x;
    if (e >= E) return;
    int d = ei[E + e];
    int pos = offs[d] + rank[e];
    int2 p; p.x = ei[e]; p.y = __float_as_int(ea[e]);
    csr[pos] = p;
}

// ---------------- per-node attention + aggregation: fp16 gathers, no-max softmax ---
__global__ void __launch_bounds__(256) agg_kernel(
        const __half* __restrict__ h1h, const float* __restrict__ as_,
        const float* __restrict__ ad_, const int* __restrict__ offs,
        const int* __restrict__ deg, const float* __restrict__ asum,
        const int2* __restrict__ csr,
        const float* __restrict__ pql, const float* __restrict__ bias,
        float* __restrict__ hout, int N) {
    int n = blockIdx.x * 4 + (threadIdx.x >> 6);
    if (n >= N) return;
    int lane = threadIdx.x & 63;
    int hd = lane >> 4;
    int c0 = lane * 2;
    int off = offs[n], dg = deg[n];
    float adn = ad_[n * NH + hd];
    float pa = pql[hd * 2 + 0], qa = pql[hd * 2 + 1];

    const __half2* h1v = (const __half2*)h1h;   // 64 half2 per row; index = n*64+lane

    // self-loop logit (loop attr = mean of incoming edge attrs; exactly 0 if deg==0)
    float sa = asum[n] / fmaxf((float)dg, 1.f);
    float ael = (dg > 0) ? (sa * pa + qa) : 0.f;
    float l0 = as_[n * NH + hd] + adn + ael;
    l0 = fmaxf(l0, NEG * l0);

    float2 hv = __half22float2(h1v[(size_t)n * 64 + lane]);
    float numS = __expf(l0);
    float denA = numS, a0A = numS * hv.x, a1A = numS * hv.y;
    float denB = 0.f,  a0B = 0.f,         a1B = 0.f;

    int i = 0;
    for (; i + 4 <= dg; i += 4) {
        int2 e0 = csr[off + i + 0];
        int2 e1 = csr[off + i + 1];
        int2 e2 = csr[off + i + 2];
        int2 e3 = csr[off + i + 3];
        __half2 q0 = h1v[(size_t)e0.x * 64 + lane];
        __half2 q1 = h1v[(size_t)e1.x * 64 + lane];
        __half2 q2 = h1v[(size_t)e2.x * 64 + lane];
        __half2 q3 = h1v[(size_t)e3.x * 64 + lane];
        float s0 = as_[e0.x * NH + hd];
        float s1 = as_[e1.x * NH + hd];
        float s2 = as_[e2.x * NH + hd];
        float s3 = as_[e3.x * NH + hd];
        float t0 = s0 + adn + __int_as_float(e0.y) * pa + qa;
        float t1 = s1 + adn + __int_as_float(e1.y) * pa + qa;
        float t2 = s2 + adn + __int_as_float(e2.y) * pa + qa;
        float t3 = s3 + adn + __int_as_float(e3.y) * pa + qa;
        t0 = fmaxf(t0, NEG * t0);
        t1 = fmaxf(t1, NEG * t1);
        t2 = fmaxf(t2, NEG * t2);
        t3 = fmaxf(t3, NEG * t3);
        float n0 = __expf(t0);
        float n1 = __expf(t1);
        float n2 = __expf(t2);
        float n3 = __expf(t3);
        float2 g0 = __half22float2(q0);
        float2 g1 = __half22float2(q1);
        float2 g2 = __half22float2(q2);
        float2 g3 = __half22float2(q3);
        denA += n0 + n2; denB += n1 + n3;
        a0A = fmaf(n0, g0.x, a0A); a0B = fmaf(n1, g1.x, a0B);
        a0A = fmaf(n2, g2.x, a0A); a0B = fmaf(n3, g3.x, a0B);
        a1A = fmaf(n0, g0.y, a1A); a1B = fmaf(n1, g1.y, a1B);
        a1A = fmaf(n2, g2.y, a1A); a1B = fmaf(n3, g3.y, a1B);
    }
    for (; i < dg; ++i) {
        int2 ep = csr[off + i];
        __half2 qs = h1v[(size_t)ep.x * 64 + lane];
        float lg = as_[ep.x * NH + hd] + adn + __int_as_float(ep.y) * pa + qa;
        lg = fmaxf(lg, NEG * lg);
        float num = __expf(lg);
        float2 gs = __half22float2(qs);
        denA += num;
        a0A = fmaf(num, gs.x, a0A);
        a1A = fmaf(num, gs.y, a1A);
    }
    float den = denA + denB;
    float a0 = a0A + a0B, a1 = a1A + a1B;
    float inv = 1.f / (den + 1e-16f);
    float o0 = a0 * inv + bias[c0];
    float o1 = a1 * inv + bias[c0 + 1];
    o0 = (o0 > 0.f) ? o0 : expm1f(o0);   // elu
    o1 = (o1 > 0.f) ? o1 : expm1f(o1);
    hout[(size_t)n * DH + c0] = o0;
    hout[(size_t)n * DH + c0 + 1] = o1;
}

// ---------------- decoder: relu(h@w1+b1)@w2+b2, fully fused ----------------
__global__ void __launch_bounds__(256) dec_kernel(
        const float* __restrict__ h, const float* __restrict__ w1,
        const float* __restrict__ b1, const float* __restrict__ w2,
        const float* __restrict__ b2, float* __restrict__ out, int N) {
    __shared__ __align__(16) float rows[32][DH];
    int tid = threadIdx.x;
    int row0 = blockIdx.x * 32;

    #pragma unroll
    for (int i = 0; i < 4; ++i) {
        int idx = tid + i * 256;
        int r = idx >> 5;
        int cq = idx & 31;
        int gr = row0 + r; if (gr > N - 1) gr = N - 1;
        ((float4*)rows[r])[cq] = ((const float4*)(h + (size_t)gr * DH))[cq];
    }
    __syncthreads();

    int wv_ = tid >> 6;
    int lane = tid & 63;
    int cg = lane & 31;
    int rh = lane >> 5;
    int rbase = wv_ * 8 + rh * 4;

    float acc[4][4];
    #pragma unroll
    for (int r = 0; r < 4; ++r)
        #pragma unroll
        for (int c = 0; c < 4; ++c) acc[r][c] = 0.f;

    #pragma unroll 2
    for (int kc = 0; kc < 32; ++kc) {
        float4 wv0 = ((const float4*)(w1 + (kc * 4 + 0) * DH))[cg];
        float4 wv1 = ((const float4*)(w1 + (kc * 4 + 1) * DH))[cg];
        float4 wv2 = ((const float4*)(w1 + (kc * 4 + 2) * DH))[cg];
        float4 wv3 = ((const float4*)(w1 + (kc * 4 + 3) * DH))[cg];
        #pragma unroll
        for (int r = 0; r < 4; ++r) {
            float4 rv = ((const float4*)rows[rbase + r])[kc];
            acc[r][0] = fmaf(rv.x, wv0.x, acc[r][0]);
            acc[r][1] = fmaf(rv.x, wv0.y, acc[r][1]);
            acc[r][2] = fmaf(rv.x, wv0.z, acc[r][2]);
            acc[r][3] = fmaf(rv.x, wv0.w, acc[r][3]);
            acc[r][0] = fmaf(rv.y, wv1.x, acc[r][0]);
            acc[r][1] = fmaf(rv.y, wv1.y, acc[r][1]);
            acc[r][2] = fmaf(rv.y, wv1.z, acc[r][2]);
            acc[r][3] = fmaf(rv.y, wv1.w, acc[r][3]);
            acc[r][0] = fmaf(rv.z, wv2.x, acc[r][0]);
            acc[r][1] = fmaf(rv.z, wv2.y, acc[r][1]);
            acc[r][2] = fmaf(rv.z, wv2.z, acc[r][2]);
            acc[r][3] = fmaf(rv.z, wv2.w, acc[r][3]);
            acc[r][0] = fmaf(rv.w, wv3.x, acc[r][0]);
            acc[r][1] = fmaf(rv.w, wv3.y, acc[r][1]);
            acc[r][2] = fmaf(rv.w, wv3.z, acc[r][2]);
            acc[r][3] = fmaf(rv.w, wv3.w, acc[r][3]);
        }
    }

    float4 b14 = ((const float4*)b1)[cg];
    float4 wA = ((const float4*)w2)[cg * 2 + 0];
    float4 wB = ((const float4*)w2)[cg * 2 + 1];
    float bb0 = b2[0], bb1 = b2[1];
    #pragma unroll
    for (int r = 0; r < 4; ++r) {
        float h0 = fmaxf(acc[r][0] + b14.x, 0.f);
        float h1v = fmaxf(acc[r][1] + b14.y, 0.f);
        float h2 = fmaxf(acc[r][2] + b14.z, 0.f);
        float h3 = fmaxf(acc[r][3] + b14.w, 0.f);
        float p0 = h0 * wA.x + h1v * wA.z + h2 * wB.x + h3 * wB.z;
        float p1 = h0 * wA.y + h1v * wA.w + h2 * wB.y + h3 * wB.w;
        #pragma unroll
        for (int o = 16; o > 0; o >>= 1) {
            p0 += __shfl_down(p0, o, 32);
            p1 += __shfl_down(p1, o, 32);
        }
        int row = row0 + rbase + r;
        if (cg == 0 && row < N) {
            out[row * 2 + 0] = p0 + bb0;
            out[row * 2 + 1] = p1 + bb1;
        }
    }
}

extern "C" void kernel_launch(void* const* d_in, const int* in_sizes, int n_in,
                              void* d_out, int out_size, void* d_ws, size_t ws_size,
                              hipStream_t stream) {
    const float* x          = (const float*)d_in[0];
    const int*   ei         = (const int*)d_in[1];
    const float* eattr      = (const float*)d_in[2];
    const float* enc_node_w = (const float*)d_in[3];
    const float* enc_node_b = (const float*)d_in[4];
    const float* enc_edge_w = (const float*)d_in[5];
    const float* enc_edge_b = (const float*)d_in[6];
    const float* lin_w      = (const float*)d_in[7];
    const float* lin_edge_w = (const float*)d_in[8];
    const float* att_src    = (const float*)d_in[9];
    const float* att_dst    = (const float*)d_in[10];
    const float* att_edge   = (const float*)d_in[11];
    const float* gat_bias   = (const float*)d_in[12];
    const float* dec_w1     = (const float*)d_in[13];
    const float* dec_b1     = (const float*)d_in[14];
    const float* dec_w2     = (const float*)d_in[15];
    const float* dec_b2     = (const float*)d_in[16];

    const int E = in_sizes[2];          // DE == 1
    const int N = in_sizes[0] / DIN;

    char* w = (char*)d_ws;
    auto alloc = [&](size_t bytes) -> void* {
        void* p = (void*)w;
        w += (bytes + 511) & ~((size_t)511);
        return p;
    };
    float*  h     = (float*)alloc((size_t)N * DH * 4);
    __half* h1h   = (__half*)alloc((size_t)N * DH * 2);
    float* as_    = (float*)alloc((size_t)N * NH * 4);
    float* ad_    = (float*)alloc((size_t)N * NH * 4);
    unsigned long long* pk = (unsigned long long*)alloc((size_t)N * 8);
    int*   rank   = (int*)alloc((size_t)E * 4);
    int*   deg    = (int*)alloc((size_t)N * 4);
    float* asum   = (float*)alloc((size_t)N * 4);
    int*   offs   = (int*)alloc((size_t)N * 4);
    int*   bsum   = (int*)alloc(64 * 4);
    int*   boff   = (int*)alloc(64 * 4);
    int2*  csr    = (int2*)alloc((size_t)E * 8);
    float* pq     = (float*)alloc(NL * NH * 2 * 4);

    hipMemsetAsync(pk, 0, (size_t)N * 8, stream);

    pq_kernel<<<NL * NH, 64, 0, stream>>>(enc_edge_w, enc_edge_b, lin_edge_w, att_edge, pq);
    enc_kernel<<<(N + 31) / 32, 256, 0, stream>>>(x, enc_node_w, enc_node_b, h, N);
    rank_kernel<<<(E + 255) / 256, 256, 0, stream>>>(ei, eattr, pk, rank, E);

    int nb = (N + 1023) / 1024;
    scan1<<<nb, 1024, 0, stream>>>(pk, offs, bsum, N);
    scan2<<<1, 64, 0, stream>>>(bsum, boff, nb);
    scan3<<<nb, 1024, 0, stream>>>(offs, boff, pk, deg, asum, N);
    scatter_kernel<<<(E + 255) / 256, 256, 0, stream>>>(ei, eattr, offs, rank, csr, E);

    for (int l = 0; l < NL; ++l) {
        layer_node<<<(N + 31) / 32, 256, 0, stream>>>(h, lin_w + (size_t)l * DH * DH,
                                                      att_src + l * DH, att_dst + l * DH,
                                                      h1h, as_, ad_, N);
        agg_kernel<<<(N + 3) / 4, 256, 0, stream>>>(h1h, as_, ad_, offs, deg, asum, csr,
                                                    pq + l * NH * 2, gat_bias + l * DH, h, N);
    }
    dec_kernel<<<(N + 31) / 32, 256, 0, stream>>>(h, dec_w1, dec_b1, dec_w2, dec_b2,
                                                  (float*)d_out, N);
}